// Round 2
// baseline (1856.306 us; speedup 1.0000x reference)
//
#include <hip/hip_runtime.h>
#include <hip/hip_bf16.h>

#define NNODES 100000
#define NEDGES 1000000
#define MM 5
#define WW 35
#define DD 3

// ---- packed per-net weight layout (float offsets, all float4-aligned) ----
#define P_SWF 0        // [35][12] start, forward cols (pad 2 zeros)
#define P_SWR 420      // [35][12] start, reversed cols
#define P_HW  840      // [3][35][36] hidden (pad col 35 = 0)
#define P_EW  4620     // [5][36] end rows 0..4 (pad col 35 = 0)
#define P_SB  4800     // [35]
#define P_HB  4835     // [3*35]
#define P_EB  4940     // [5]
#define NET_F 4948     // per-net float stride

// ---- workspace layout (bytes) ----
#define WS_AGG    0u          // float[N]
#define WS_DEG    400000u     // int[N]
#define WS_STATS  800000u     // float[2]
#define WS_DEGMAX 800008u     // int
#define WS_CNTS   800012u     // int[2]  (pos count, neg count)
#define WS_ZERO_BYTES 800020u
#define WS_WTS    800032u     // float[2*NET_F]
#define WS_LIST   839616u     // int[E]  two-ended: pos from 0 up, neg from E-1 down

__global__ void __launch_bounds__(256) prep_weights_kernel(
    const float* __restrict__ Rsw, const float* __restrict__ Rsb,
    const float* __restrict__ Rhw, const float* __restrict__ Rhb,
    const float* __restrict__ Rew, const float* __restrict__ Reb,
    const float* __restrict__ Psw, const float* __restrict__ Psb,
    const float* __restrict__ Phw, const float* __restrict__ Phb,
    const float* __restrict__ Pew, const float* __restrict__ Peb,
    float* __restrict__ wp)
{
    const int tid = blockIdx.x * blockDim.x + threadIdx.x;
    const int stride = gridDim.x * blockDim.x;
    #pragma unroll 1
    for (int n = 0; n < 2; ++n) {
        const float* sw = n ? Psw : Rsw;
        const float* sb = n ? Psb : Rsb;
        const float* hw = n ? Phw : Rhw;
        const float* hb = n ? Phb : Rhb;
        const float* ew = n ? Pew : Rew;
        const float* eb = n ? Peb : Reb;
        float* o = wp + n * NET_F;
        for (int g = tid; g < WW * 12; g += stride) {
            int j = g / 12, c = g - j * 12;
            o[P_SWF + g] = (c < 10) ? sw[j * 10 + c] : 0.0f;
            o[P_SWR + g] = (c < 10) ? sw[j * 10 + 9 - c] : 0.0f;
        }
        for (int g = tid; g < DD * WW * 36; g += stride) {
            int r = g / 36, c = g - r * 36;     // r = l*35 + j
            o[P_HW + g] = (c < WW) ? hw[r * WW + c] : 0.0f;
        }
        for (int g = tid; g < MM * 36; g += stride) {
            int k = g / 36, c = g - k * 36;
            o[P_EW + g] = (c < WW) ? ew[k * WW + c] : 0.0f;
        }
        for (int g = tid; g < WW; g += stride)      o[P_SB + g] = sb[g];
        for (int g = tid; g < DD * WW; g += stride) o[P_HB + g] = hb[g];
        for (int g = tid; g < MM; g += stride)      o[P_EB + g] = eb[g];
    }
}

// wave-aggregated two-ended compaction by outcome sign
__global__ void __launch_bounds__(256) sort_kernel(
    const float* __restrict__ outcome, int* __restrict__ list, int* __restrict__ cnts)
{
    const int lane = threadIdx.x & 63;
    for (int e = blockIdx.x * blockDim.x + threadIdx.x; ; ) {
        // wave-uniform continuation check
        int base = e - lane + 0;  (void)base;
        bool inb = e < NEDGES;
        if (!__any(inb)) break;
        bool pos = inb && (outcome[inb ? e : 0] > 0.0f);
        bool neg = inb && !pos;

        unsigned long long mp = __ballot(pos);
        unsigned long long mn = __ballot(neg);
        int np = __popcll(mp), nn = __popcll(mn);
        unsigned long long below = (lane == 0) ? 0ull : (~0ull >> (64 - lane));
        int pp = __popcll(mp & below);
        int pn = __popcll(mn & below);

        int bp = 0, bn = 0;
        if (lane == 0) {
            if (np) bp = atomicAdd(&cnts[0], np);
            if (nn) bn = atomicAdd(&cnts[1], nn);
        }
        bp = __shfl(bp, 0);
        bn = __shfl(bn, 0);
        if (pos) list[bp + pp] = e;
        if (neg) list[NEDGES - 1 - (bn + pn)] = e;

        e += gridDim.x * blockDim.x;
    }
}

__device__ __forceinline__ float sigmoidf(float z) {
    return 1.0f / (1.0f + __expf(-z));
}

// one hidden layer: dst[0..34] = relu(W*src + b), src[35] must be 0 pad
#define HIDDEN_LAYER(dst, src, L)                                              \
    {                                                                          \
        _Pragma("unroll")                                                      \
        for (int j = 0; j < WW; ++j) {                                         \
            float acc = hb[(L) * WW + j];                                      \
            _Pragma("unroll")                                                  \
            for (int q = 0; q < 9; ++q) {                                      \
                float4 wv = hw4[((L) * WW + j) * 9 + q];                       \
                acc += wv.x * src[4 * q + 0] + wv.y * src[4 * q + 1]           \
                     + wv.z * src[4 * q + 2] + wv.w * src[4 * q + 3];          \
            }                                                                  \
            dst[j] = fmaxf(acc, 0.0f);                                         \
        }                                                                      \
    }

__global__ void __launch_bounds__(256, 2) edge_kernel(
    const float* __restrict__ score,
    const int*   __restrict__ edge_idx,
    const float* __restrict__ wp,
    const int*   __restrict__ list,
    const int*   __restrict__ cnts,
    float* __restrict__ agg, int* __restrict__ deg)
{
    const int cp = cnts[0];   // uniform (s_load)

    #pragma unroll 1
    for (int combo = 0; combo < 4; ++combo) {
        // A: R,pos,fwd,+,tgt0  B: R,neg,rev,+,tgt5  C: P,pos,rev,-,tgt5  D: P,neg,fwd,-,tgt0
        const int  useR   = (combo < 2);
        const int  revst  = (combo == 1 || combo == 2);
        const float sgn   = useR ? 1.0f : -1.0f;
        const int  lo     = (combo == 0 || combo == 2) ? 0 : cp;
        const int  hi     = (combo == 0 || combo == 2) ? cp : NEDGES;

        const float*  net = wp + (useR ? 0 : NET_F);
        const float4* sw4 = (const float4*)(net + (revst ? P_SWR : P_SWF));
        const float4* hw4 = (const float4*)(net + P_HW);
        const float4* ew4 = (const float4*)(net + P_EW);
        const float*  sb  = net + P_SB;
        const float*  hb  = net + P_HB;
        const float*  eb  = net + P_EB;

        #pragma unroll 1
        for (int base = lo + (int)blockIdx.x * 256; base < hi; base += (int)gridDim.x * 256) {
            const int  i      = base + (int)threadIdx.x;
            const bool active = (i < hi);
            const int  e      = active ? list[i] : list[lo];

            int nv[10];
            float xin[12];
            #pragma unroll
            for (int j = 0; j < 10; ++j) {
                nv[j]  = edge_idx[e * 10 + j];
                xin[j] = score[nv[j]];
            }
            xin[10] = 0.0f; xin[11] = 0.0f;

            float h[36], t[36];
            h[35] = 0.0f; t[35] = 0.0f;

            // start layer
            #pragma unroll
            for (int j = 0; j < WW; ++j) {
                float acc = sb[j];
                #pragma unroll
                for (int q = 0; q < 3; ++q) {
                    float4 wv = sw4[j * 3 + q];
                    acc += wv.x * xin[4 * q + 0] + wv.y * xin[4 * q + 1]
                         + wv.z * xin[4 * q + 2] + wv.w * xin[4 * q + 3];
                }
                h[j] = fmaxf(acc, 0.0f);
            }

            HIDDEN_LAYER(t, h, 0)
            HIDDEN_LAYER(h, t, 1)
            HIDDEN_LAYER(t, h, 2)

            // end layer rows 0..4 + sigmoid
            float val[MM];
            #pragma unroll
            for (int k = 0; k < MM; ++k) {
                float acc = eb[k];
                #pragma unroll
                for (int q = 0; q < 9; ++q) {
                    float4 wv = ew4[k * 9 + q];
                    acc += wv.x * t[4 * q + 0] + wv.y * t[4 * q + 1]
                         + wv.z * t[4 * q + 2] + wv.w * t[4 * q + 3];
                }
                val[k] = sgn * sigmoidf(acc);
            }

            if (active) {
                #pragma unroll
                for (int k = 0; k < MM; ++k) {
                    // tgt slot k or 5+k (uniform select, static indexing)
                    int tgt = revst ? nv[5 + k] : nv[k];
                    atomicAdd(&deg[tgt], 1);
                    unsafeAtomicAdd(&agg[tgt], val[k]);
                }
            }
        }
    }
}

__global__ void __launch_bounds__(256) degmax_kernel(const int* __restrict__ deg,
                                                     int* __restrict__ degmax)
{
    int m = 0;
    for (int i = blockIdx.x * blockDim.x + threadIdx.x; i < NNODES;
         i += gridDim.x * blockDim.x)
        m = max(m, deg[i]);
    #pragma unroll
    for (int off = 32; off; off >>= 1) m = max(m, __shfl_down(m, off));
    __shared__ int sm[4];
    if ((threadIdx.x & 63) == 0) sm[threadIdx.x >> 6] = m;
    __syncthreads();
    if (threadIdx.x == 0) {
        int mm = sm[0];
        #pragma unroll
        for (int w = 1; w < 4; ++w) mm = max(mm, sm[w]);
        atomicMax(degmax, mm);
    }
}

__global__ void __launch_bounds__(256) stats_kernel(const float* __restrict__ score,
                                                    const float* __restrict__ agg,
                                                    const int* __restrict__ degmax,
                                                    float* __restrict__ stats)
{
    const float scale = 2.0f / (float)(*degmax);
    float s = 0.0f, s2 = 0.0f;
    for (int i = blockIdx.x * blockDim.x + threadIdx.x; i < NNODES;
         i += gridDim.x * blockDim.x) {
        float v = fmaf(agg[i], scale, score[i]);
        s += v;
        s2 = fmaf(v, v, s2);
    }
    #pragma unroll
    for (int off = 32; off; off >>= 1) {
        s  += __shfl_down(s, off);
        s2 += __shfl_down(s2, off);
    }
    __shared__ float ssum[4], ssq[4];
    if ((threadIdx.x & 63) == 0) { ssum[threadIdx.x >> 6] = s; ssq[threadIdx.x >> 6] = s2; }
    __syncthreads();
    if (threadIdx.x == 0) {
        float a = 0.0f, b = 0.0f;
        #pragma unroll
        for (int w = 0; w < 4; ++w) { a += ssum[w]; b += ssq[w]; }
        unsafeAtomicAdd(&stats[0], a);
        unsafeAtomicAdd(&stats[1], b);
    }
}

__global__ void __launch_bounds__(256) finalize_kernel(const float* __restrict__ score,
                                                       const float* __restrict__ agg,
                                                       const int* __restrict__ degmax,
                                                       const float* __restrict__ stats,
                                                       float* __restrict__ out)
{
    const float scale = 2.0f / (float)(*degmax);
    const float sum = stats[0], sumsq = stats[1];
    const float mean = sum * (1.0f / NNODES);
    const float rn = 1.0f / sqrtf(sumsq - sum * mean);
    for (int i = blockIdx.x * blockDim.x + threadIdx.x; i < NNODES;
         i += gridDim.x * blockDim.x) {
        float v = fmaf(agg[i], scale, score[i]);
        out[i] = (v - mean) * rn;
    }
}

extern "C" void kernel_launch(void* const* d_in, const int* in_sizes, int n_in,
                              void* d_out, int out_size, void* d_ws, size_t ws_size,
                              hipStream_t stream)
{
    const float* score    = (const float*)d_in[0];
    const int*   edge_idx = (const int*)  d_in[1];
    const float* outcome  = (const float*)d_in[2];
    const float* Rsw = (const float*)d_in[3];
    const float* Rsb = (const float*)d_in[4];
    const float* Rhw = (const float*)d_in[5];
    const float* Rhb = (const float*)d_in[6];
    const float* Rew = (const float*)d_in[7];
    const float* Reb = (const float*)d_in[8];
    const float* Psw = (const float*)d_in[9];
    const float* Psb = (const float*)d_in[10];
    const float* Phw = (const float*)d_in[11];
    const float* Phb = (const float*)d_in[12];
    const float* Pew = (const float*)d_in[13];
    const float* Peb = (const float*)d_in[14];
    float* out = (float*)d_out;

    char* ws = (char*)d_ws;
    float* agg    = (float*)(ws + WS_AGG);
    int*   deg    = (int*)  (ws + WS_DEG);
    float* stats  = (float*)(ws + WS_STATS);
    int*   degmax = (int*)  (ws + WS_DEGMAX);
    int*   cnts   = (int*)  (ws + WS_CNTS);
    float* wts    = (float*)(ws + WS_WTS);
    int*   list   = (int*)  (ws + WS_LIST);

    hipMemsetAsync(d_ws, 0, WS_ZERO_BYTES, stream);

    prep_weights_kernel<<<64, 256, 0, stream>>>(Rsw, Rsb, Rhw, Rhb, Rew, Reb,
                                                Psw, Psb, Phw, Phb, Pew, Peb, wts);
    sort_kernel<<<1024, 256, 0, stream>>>(outcome, list, cnts);

    edge_kernel<<<2048, 256, 0, stream>>>(score, edge_idx, wts, list, cnts, agg, deg);

    const int nb = (NNODES + 255) / 256;
    degmax_kernel  <<<nb, 256, 0, stream>>>(deg, degmax);
    stats_kernel   <<<nb, 256, 0, stream>>>(score, agg, degmax, stats);
    finalize_kernel<<<nb, 256, 0, stream>>>(score, agg, degmax, stats, out);
}

// Round 3
// 1421.970 us; speedup vs baseline: 1.3054x; 1.3054x over previous
//
#include <hip/hip_runtime.h>
#include <hip/hip_bf16.h>
#include <hip/hip_fp16.h>

typedef _Float16 f16x8 __attribute__((ext_vector_type(8)));
typedef float    f32x4 __attribute__((ext_vector_type(4)));

#define NNODES 100000
#define NEDGES 1000000

// ---- workspace layout (bytes) ----
#define WS_AGG    0u          // float[N]
#define WS_DEG    400000u     // int[N]
#define WS_STATS  800000u     // float[2]
#define WS_DEGMAX 800008u     // int
#define WS_CNTS   800012u     // int[2]
#define WS_ZERO_BYTES 800020u
#define WS_FRAGS  800032u     // ushort[52][2][64][8]  (106496 B, 16B aligned)
#define WS_LIST   906528u     // int[E]

// tiles per net: 0-2 L0 fwd mt, 3-5 L0 rev mt, 6-23 L1-3 [(L-1)*6 + mt*2 + kt], 24-25 L4 kt
#define NTILES_PER_NET 26

__global__ void __launch_bounds__(64) prep_frag_kernel(
    const float* __restrict__ Rsw, const float* __restrict__ Rsb,
    const float* __restrict__ Rhw, const float* __restrict__ Rhb,
    const float* __restrict__ Rew, const float* __restrict__ Reb,
    const float* __restrict__ Psw, const float* __restrict__ Psb,
    const float* __restrict__ Phw, const float* __restrict__ Phb,
    const float* __restrict__ Pew, const float* __restrict__ Peb,
    unsigned short* __restrict__ frags)
{
    const int t = blockIdx.x;          // 0..51
    const int l = threadIdx.x;         // 0..63
    const int net = t / NTILES_PER_NET;
    const int tt  = t % NTILES_PER_NET;
    const float *sw, *sb, *hw, *hb, *ew, *eb;
    if (net == 0) { sw=Rsw; sb=Rsb; hw=Rhw; hb=Rhb; ew=Rew; eb=Reb; }
    else          { sw=Psw; sb=Psb; hw=Phw; hb=Phb; ew=Pew; eb=Peb; }

    int layer, mt, kt = 0, rev = 0;
    if (tt < 6)       { layer = 0; rev = (tt >= 3); mt = tt % 3; }
    else if (tt < 24) { int u = tt - 6; layer = 1 + u / 6; u %= 6; mt = u / 2; kt = u % 2; }
    else              { layer = 4; mt = 0; kt = tt - 24; }

    const int m     = mt * 16 + (l & 15);
    const int kbase = kt * 32 + (l >> 4) * 8;

    unsigned short hi8[8], lo8[8];
    #pragma unroll
    for (int j = 0; j < 8; ++j) {
        const int k = kbase + j;
        float v = 0.0f;
        if (layer == 0) {
            if (m < 35) { if (k < 10) v = sw[m * 10 + (rev ? 9 - k : k)];
                          else if (k == 10) v = sb[m]; }
        } else if (layer <= 3) {
            if (m < 35) { if (k < 35) v = hw[(layer - 1) * 1225 + m * 35 + k];
                          else if (k == 35) v = hb[(layer - 1) * 35 + m]; }
        } else {
            if (m < 5)  { if (k < 35) v = ew[m * 35 + k];
                          else if (k == 35) v = eb[m]; }
        }
        _Float16 h = (_Float16)v;
        _Float16 lo = (_Float16)(v - (float)h);
        hi8[j] = __builtin_bit_cast(unsigned short, h);
        lo8[j] = __builtin_bit_cast(unsigned short, lo);
    }
    unsigned short* bh = frags + ((size_t)(t * 2 + 0) * 64 + l) * 8;
    unsigned short* bl = frags + ((size_t)(t * 2 + 1) * 64 + l) * 8;
    #pragma unroll
    for (int j = 0; j < 8; ++j) { bh[j] = hi8[j]; bl[j] = lo8[j]; }
}

// wave-aggregated two-ended compaction by outcome sign
__global__ void __launch_bounds__(256) sort_kernel(
    const float* __restrict__ outcome, int* __restrict__ list, int* __restrict__ cnts)
{
    const int lane = threadIdx.x & 63;
    for (int e = blockIdx.x * blockDim.x + threadIdx.x; ; e += gridDim.x * blockDim.x) {
        bool inb = e < NEDGES;
        if (!__any(inb)) break;
        bool pos = inb && (outcome[inb ? e : 0] > 0.0f);
        bool neg = inb && !pos;
        unsigned long long mp = __ballot(pos);
        unsigned long long mn = __ballot(neg);
        int np = __popcll(mp), nn = __popcll(mn);
        unsigned long long below = (lane == 0) ? 0ull : (~0ull >> (64 - lane));
        int pp = __popcll(mp & below);
        int pn = __popcll(mn & below);
        int bp = 0, bn = 0;
        if (lane == 0) {
            if (np) bp = atomicAdd(&cnts[0], np);
            if (nn) bn = atomicAdd(&cnts[1], nn);
        }
        bp = __shfl(bp, 0);
        bn = __shfl(bn, 0);
        if (pos) list[bp + pp] = e;
        if (neg) list[NEDGES - 1 - (bn + pn)] = e;
    }
}

__global__ void __launch_bounds__(256) deg_kernel(const int* __restrict__ edge_idx,
                                                  int* __restrict__ deg)
{
    for (int i = blockIdx.x * 256 + threadIdx.x; i < NEDGES * 10; i += gridDim.x * 256)
        atomicAdd(&deg[edge_idx[i]], 1);
}

__device__ __forceinline__ unsigned int pk16(_Float16 a, _Float16 b) {
    return (unsigned int)__builtin_bit_cast(unsigned short, a) |
           ((unsigned int)__builtin_bit_cast(unsigned short, b) << 16);
}

// store one M-tile of activations (f32x4 per lane) as hi/lo f16 into swizzled LDS
__device__ __forceinline__ void trans_store(unsigned int* hb, int n, int rb, int mt, f32x4 v)
{
    _Float16 h0 = (_Float16)v[0], h1 = (_Float16)v[1], h2 = (_Float16)v[2], h3 = (_Float16)v[3];
    float r0 = v[0] - (float)h0, r1 = v[1] - (float)h1, r2 = v[2] - (float)h2, r3 = v[3] - (float)h3;
    unsigned int hd0 = pk16(h0, h1), hd1 = pk16(h2, h3);
    unsigned int ld0 = pk16((_Float16)r0, (_Float16)r1), ld1 = pk16((_Float16)r2, (_Float16)r3);
    const int b  = 2 * mt + (rb >> 1);
    const int bp = b ^ (n & 7);
    const int dw = n * 32 + (bp << 2) + ((rb & 1) << 1);
    *reinterpret_cast<uint2*>(hb + dw)       = make_uint2(hd0, hd1);
    *reinterpret_cast<uint2*>(hb + 512 + dw) = make_uint2(ld0, ld1);
}

__device__ __forceinline__ f16x8 read_b(const unsigned int* hb, int n, int kb, int kt, int lobuf)
{
    const int b  = kt * 4 + kb;
    const int bp = b ^ (n & 7);
    uint4 d = *reinterpret_cast<const uint4*>(hb + lobuf * 512 + n * 32 + (bp << 2));
    return __builtin_bit_cast(f16x8, d);
}

#define MF(acc, WH, WL, BH, BL)                                                    \
    acc = __builtin_amdgcn_mfma_f32_16x16x32_f16(WH, BH, acc, 0, 0, 0);            \
    acc = __builtin_amdgcn_mfma_f32_16x16x32_f16(WH, BL, acc, 0, 0, 0);            \
    acc = __builtin_amdgcn_mfma_f32_16x16x32_f16(WL, BH, acc, 0, 0, 0);

// relu 3 tiles, set bias-one (m=35), store to LDS
#define TRANSITION(X0, X1, X2)                                                     \
    {                                                                              \
        _Pragma("unroll")                                                          \
        for (int r = 0; r < 4; ++r) {                                              \
            X0[r] = fmaxf(X0[r], 0.0f);                                            \
            X1[r] = fmaxf(X1[r], 0.0f);                                            \
            X2[r] = fmaxf(X2[r], 0.0f);                                            \
        }                                                                          \
        if (kb == 0) X2[3] = 1.0f;                                                 \
        trans_store(hb, n, kb, 0, X0);                                             \
        trans_store(hb, n, kb, 1, X1);                                             \
        trans_store(hb, n, kb, 2, X2);                                             \
    }

#define HLAYER(U0, C0, C1, C2)                                                     \
    {                                                                              \
        f16x8 bh0 = read_b(hb, n, kb, 0, 0), bl0 = read_b(hb, n, kb, 0, 1);        \
        f16x8 bh1 = read_b(hb, n, kb, 1, 0), bl1 = read_b(hb, n, kb, 1, 1);        \
        C0 = z4; C1 = z4; C2 = z4;                                                 \
        MF(C0, wh[(U0) + 0], wl[(U0) + 0], bh0, bl0)                               \
        MF(C0, wh[(U0) + 1], wl[(U0) + 1], bh1, bl1)                               \
        MF(C1, wh[(U0) + 2], wl[(U0) + 2], bh0, bl0)                               \
        MF(C1, wh[(U0) + 3], wl[(U0) + 3], bh1, bl1)                               \
        MF(C2, wh[(U0) + 4], wl[(U0) + 4], bh0, bl0)                               \
        MF(C2, wh[(U0) + 5], wl[(U0) + 5], bh1, bl1)                               \
    }

__global__ void __launch_bounds__(256, 2) edge_kernel(
    const float* __restrict__ score,
    const int*   __restrict__ edge_idx,
    const unsigned short* __restrict__ frags,
    const int*   __restrict__ list,
    const int*   __restrict__ cnts,
    float* __restrict__ agg)
{
    __shared__ unsigned int hbuf[4][1024];
    const int tid  = threadIdx.x;
    const int wv   = tid >> 6;
    const int lane = tid & 63;
    const int n    = lane & 15;
    const int kb   = lane >> 4;
    unsigned int* hb = &hbuf[wv][0];

    for (int i = lane; i < 1024; i += 64) hb[i] = 0;   // zero pad region (intra-wave)

    const int gw    = blockIdx.x * 4 + wv;
    const int combo = gw & 3;
    const int wci   = gw >> 2;

    const int cp   = cnts[0];
    const int useR = (combo < 2);
    const int rev  = (combo == 1 || combo == 2);
    const float sgn = useR ? 1.0f : -1.0f;
    const int lo_  = (combo == 0 || combo == 2) ? 0 : cp;
    const int hi_  = (combo == 0 || combo == 2) ? cp : NEDGES;
    const int cnt  = hi_ - lo_;
    const int revoff = rev ? 5 : 0;
    const int t0   = useR ? 0 : NTILES_PER_NET;

    // resident weight fragments
    f16x8 wh[18], wl[18];
    #pragma unroll
    for (int u = 0; u < 18; ++u) {
        const int t = t0 + 6 + u;
        wh[u] = *reinterpret_cast<const f16x8*>(frags + ((size_t)(t * 2 + 0) * 64 + lane) * 8);
        wl[u] = *reinterpret_cast<const f16x8*>(frags + ((size_t)(t * 2 + 1) * 64 + lane) * 8);
    }
    f16x8 w0h[3], w0l[3], w4h[2], w4l[2];
    #pragma unroll
    for (int mt = 0; mt < 3; ++mt) {
        const int t = t0 + (rev ? 3 : 0) + mt;
        w0h[mt] = *reinterpret_cast<const f16x8*>(frags + ((size_t)(t * 2 + 0) * 64 + lane) * 8);
        w0l[mt] = *reinterpret_cast<const f16x8*>(frags + ((size_t)(t * 2 + 1) * 64 + lane) * 8);
    }
    #pragma unroll
    for (int kt = 0; kt < 2; ++kt) {
        const int t = t0 + 24 + kt;
        w4h[kt] = *reinterpret_cast<const f16x8*>(frags + ((size_t)(t * 2 + 0) * 64 + lane) * 8);
        w4l[kt] = *reinterpret_cast<const f16x8*>(frags + ((size_t)(t * 2 + 1) * 64 + lane) * 8);
    }

    const f32x4 z4 = {0.0f, 0.0f, 0.0f, 0.0f};

    #pragma unroll 1
    for (int base = wci * 16; base < cnt; base += (int)gridDim.x * 16) {
        const bool act = (base + n) < cnt;
        const int  ed  = list[act ? (lo_ + base + n) : lo_];

        // gather x (forward order always; reversal handled by SWR weight tiles)
        float sc[8];
        const int k0 = kb * 8;
        #pragma unroll
        for (int j = 0; j < 8; ++j) {
            const int k = k0 + j;
            const int id = (k < 10) ? edge_idx[ed * 10 + k] : 0;
            sc[j] = (k < 10) ? score[id] : 0.0f;
        }
        if (kb == 1) sc[2] = 1.0f;   // bias-one at k=10

        f16x8 bxh, bxl;
        #pragma unroll
        for (int j = 0; j < 8; ++j) {
            _Float16 h = (_Float16)sc[j];
            bxh[j] = h;
            bxl[j] = (_Float16)(sc[j] - (float)h);
        }

        // L0
        f32x4 a0 = z4, a1 = z4, a2 = z4;
        MF(a0, w0h[0], w0l[0], bxh, bxl)
        MF(a1, w0h[1], w0l[1], bxh, bxl)
        MF(a2, w0h[2], w0l[2], bxh, bxl)
        TRANSITION(a0, a1, a2)

        f32x4 c0, c1, c2;
        HLAYER(0, c0, c1, c2)
        TRANSITION(c0, c1, c2)
        HLAYER(6, c0, c1, c2)
        TRANSITION(c0, c1, c2)
        HLAYER(12, c0, c1, c2)
        TRANSITION(c0, c1, c2)

        // L4
        f32x4 c4 = z4;
        {
            f16x8 bh0 = read_b(hb, n, kb, 0, 0), bl0 = read_b(hb, n, kb, 0, 1);
            f16x8 bh1 = read_b(hb, n, kb, 1, 0), bl1 = read_b(hb, n, kb, 1, 1);
            MF(c4, w4h[0], w4l[0], bh0, bl0)
            MF(c4, w4h[1], w4l[1], bh1, bl1)
        }

        // sigmoid + signed scatter: out row q = kb*4 + r (q < 5), edge-slot n
        #pragma unroll
        for (int r = 0; r < 4; ++r) {
            const int q = kb * 4 + r;
            if (act && q < 5) {
                const float v = sgn / (1.0f + __expf(-c4[r]));
                const int tgt = edge_idx[ed * 10 + revoff + q];
                unsafeAtomicAdd(&agg[tgt], v);
            }
        }
    }
}

__global__ void __launch_bounds__(256) degmax_kernel(const int* __restrict__ deg,
                                                     int* __restrict__ degmax)
{
    int m = 0;
    for (int i = blockIdx.x * blockDim.x + threadIdx.x; i < NNODES;
         i += gridDim.x * blockDim.x)
        m = max(m, deg[i]);
    #pragma unroll
    for (int off = 32; off; off >>= 1) m = max(m, __shfl_down(m, off));
    __shared__ int sm[4];
    if ((threadIdx.x & 63) == 0) sm[threadIdx.x >> 6] = m;
    __syncthreads();
    if (threadIdx.x == 0) {
        int mm = sm[0];
        #pragma unroll
        for (int w = 1; w < 4; ++w) mm = max(mm, sm[w]);
        atomicMax(degmax, mm);
    }
}

__global__ void __launch_bounds__(256) stats_kernel(const float* __restrict__ score,
                                                    const float* __restrict__ agg,
                                                    const int* __restrict__ degmax,
                                                    float* __restrict__ stats)
{
    const float scale = 2.0f / (float)(*degmax);
    float s = 0.0f, s2 = 0.0f;
    for (int i = blockIdx.x * blockDim.x + threadIdx.x; i < NNODES;
         i += gridDim.x * blockDim.x) {
        float v = fmaf(agg[i], scale, score[i]);
        s += v;
        s2 = fmaf(v, v, s2);
    }
    #pragma unroll
    for (int off = 32; off; off >>= 1) {
        s  += __shfl_down(s, off);
        s2 += __shfl_down(s2, off);
    }
    __shared__ float ssum[4], ssq[4];
    if ((threadIdx.x & 63) == 0) { ssum[threadIdx.x >> 6] = s; ssq[threadIdx.x >> 6] = s2; }
    __syncthreads();
    if (threadIdx.x == 0) {
        float a = 0.0f, b = 0.0f;
        #pragma unroll
        for (int w = 0; w < 4; ++w) { a += ssum[w]; b += ssq[w]; }
        unsafeAtomicAdd(&stats[0], a);
        unsafeAtomicAdd(&stats[1], b);
    }
}

__global__ void __launch_bounds__(256) finalize_kernel(const float* __restrict__ score,
                                                       const float* __restrict__ agg,
                                                       const int* __restrict__ degmax,
                                                       const float* __restrict__ stats,
                                                       float* __restrict__ out)
{
    const float scale = 2.0f / (float)(*degmax);
    const float sum = stats[0], sumsq = stats[1];
    const float mean = sum * (1.0f / NNODES);
    const float rn = 1.0f / sqrtf(sumsq - sum * mean);
    for (int i = blockIdx.x * blockDim.x + threadIdx.x; i < NNODES;
         i += gridDim.x * blockDim.x) {
        float v = fmaf(agg[i], scale, score[i]);
        out[i] = (v - mean) * rn;
    }
}

extern "C" void kernel_launch(void* const* d_in, const int* in_sizes, int n_in,
                              void* d_out, int out_size, void* d_ws, size_t ws_size,
                              hipStream_t stream)
{
    const float* score    = (const float*)d_in[0];
    const int*   edge_idx = (const int*)  d_in[1];
    const float* outcome  = (const float*)d_in[2];
    const float* Rsw = (const float*)d_in[3];
    const float* Rsb = (const float*)d_in[4];
    const float* Rhw = (const float*)d_in[5];
    const float* Rhb = (const float*)d_in[6];
    const float* Rew = (const float*)d_in[7];
    const float* Reb = (const float*)d_in[8];
    const float* Psw = (const float*)d_in[9];
    const float* Psb = (const float*)d_in[10];
    const float* Phw = (const float*)d_in[11];
    const float* Phb = (const float*)d_in[12];
    const float* Pew = (const float*)d_in[13];
    const float* Peb = (const float*)d_in[14];
    float* out = (float*)d_out;

    char* ws = (char*)d_ws;
    float*          agg    = (float*)(ws + WS_AGG);
    int*            deg    = (int*)  (ws + WS_DEG);
    float*          stats  = (float*)(ws + WS_STATS);
    int*            degmax = (int*)  (ws + WS_DEGMAX);
    int*            cnts   = (int*)  (ws + WS_CNTS);
    unsigned short* frags  = (unsigned short*)(ws + WS_FRAGS);
    int*            list   = (int*)  (ws + WS_LIST);

    hipMemsetAsync(d_ws, 0, WS_ZERO_BYTES, stream);

    prep_frag_kernel<<<52, 64, 0, stream>>>(Rsw, Rsb, Rhw, Rhb, Rew, Reb,
                                            Psw, Psb, Phw, Phb, Pew, Peb, frags);
    sort_kernel<<<1024, 256, 0, stream>>>(outcome, list, cnts);
    deg_kernel<<<2048, 256, 0, stream>>>(edge_idx, deg);

    edge_kernel<<<512, 256, 0, stream>>>(score, edge_idx, frags, list, cnts, agg);

    const int nb = (NNODES + 255) / 256;
    degmax_kernel  <<<nb, 256, 0, stream>>>(deg, degmax);
    stats_kernel   <<<nb, 256, 0, stream>>>(score, agg, degmax, stats);
    finalize_kernel<<<nb, 256, 0, stream>>>(score, agg, degmax, stats, out);
}

// Round 4
// 1367.940 us; speedup vs baseline: 1.3570x; 1.0395x over previous
//
#include <hip/hip_runtime.h>
#include <hip/hip_bf16.h>
#include <hip/hip_fp16.h>

typedef _Float16 f16x8 __attribute__((ext_vector_type(8)));
typedef float    f32x4 __attribute__((ext_vector_type(4)));

#define NNODES 100000
#define NEDGES 1000000

// ---- workspace layout (bytes) ----
#define WS_AGG    0u          // float[N]
#define WS_DEG    400000u     // int[N]
#define WS_STATS  800000u     // float[2]
#define WS_DEGMAX 800008u     // int
#define WS_CNTS   800012u     // int[2]
#define WS_ZERO_BYTES 800020u
#define WS_FRAGS  800032u     // ushort[52][2][64][8]  (106496 B, 16B aligned)
#define WS_LIST   906528u     // int[E]

// tiles per net: 0-2 L0 fwd mt, 3-5 L0 rev mt, 6-23 L1-3 [(L-1)*6 + mt*2 + kt], 24-25 L4 kt
#define NTILES_PER_NET 26

__global__ void __launch_bounds__(64) prep_frag_kernel(
    const float* __restrict__ Rsw, const float* __restrict__ Rsb,
    const float* __restrict__ Rhw, const float* __restrict__ Rhb,
    const float* __restrict__ Rew, const float* __restrict__ Reb,
    const float* __restrict__ Psw, const float* __restrict__ Psb,
    const float* __restrict__ Phw, const float* __restrict__ Phb,
    const float* __restrict__ Pew, const float* __restrict__ Peb,
    unsigned short* __restrict__ frags)
{
    const int t = blockIdx.x;          // 0..51
    const int l = threadIdx.x;         // 0..63
    const int net = t / NTILES_PER_NET;
    const int tt  = t % NTILES_PER_NET;
    const float *sw, *sb, *hw, *hb, *ew, *eb;
    if (net == 0) { sw=Rsw; sb=Rsb; hw=Rhw; hb=Rhb; ew=Rew; eb=Reb; }
    else          { sw=Psw; sb=Psb; hw=Phw; hb=Phb; ew=Pew; eb=Peb; }

    int layer, mt, kt = 0, rev = 0;
    if (tt < 6)       { layer = 0; rev = (tt >= 3); mt = tt % 3; }
    else if (tt < 24) { int u = tt - 6; layer = 1 + u / 6; u %= 6; mt = u / 2; kt = u % 2; }
    else              { layer = 4; mt = 0; kt = tt - 24; }

    const int m     = mt * 16 + (l & 15);
    const int kbase = kt * 32 + (l >> 4) * 8;

    unsigned short hi8[8], lo8[8];
    #pragma unroll
    for (int j = 0; j < 8; ++j) {
        const int k = kbase + j;
        float v = 0.0f;
        if (layer == 0) {
            if (m < 35) { if (k < 10) v = sw[m * 10 + (rev ? 9 - k : k)];
                          else if (k == 10) v = sb[m]; }
        } else if (layer <= 3) {
            if (m < 35) { if (k < 35) v = hw[(layer - 1) * 1225 + m * 35 + k];
                          else if (k == 35) v = hb[(layer - 1) * 35 + m]; }
        } else {
            if (m < 5)  { if (k < 35) v = ew[m * 35 + k];
                          else if (k == 35) v = eb[m]; }
        }
        _Float16 h = (_Float16)v;
        _Float16 lo = (_Float16)(v - (float)h);
        hi8[j] = __builtin_bit_cast(unsigned short, h);
        lo8[j] = __builtin_bit_cast(unsigned short, lo);
    }
    unsigned short* bh = frags + ((size_t)(t * 2 + 0) * 64 + l) * 8;
    unsigned short* bl = frags + ((size_t)(t * 2 + 1) * 64 + l) * 8;
    #pragma unroll
    for (int j = 0; j < 8; ++j) { bh[j] = hi8[j]; bl[j] = lo8[j]; }
}

// wave-aggregated two-ended compaction by outcome sign
__global__ void __launch_bounds__(256) sort_kernel(
    const float* __restrict__ outcome, int* __restrict__ list, int* __restrict__ cnts)
{
    const int lane = threadIdx.x & 63;
    for (int e = blockIdx.x * blockDim.x + threadIdx.x; ; e += gridDim.x * blockDim.x) {
        bool inb = e < NEDGES;
        if (!__any(inb)) break;
        bool pos = inb && (outcome[inb ? e : 0] > 0.0f);
        bool neg = inb && !pos;
        unsigned long long mp = __ballot(pos);
        unsigned long long mn = __ballot(neg);
        int np = __popcll(mp), nn = __popcll(mn);
        unsigned long long below = (lane == 0) ? 0ull : (~0ull >> (64 - lane));
        int pp = __popcll(mp & below);
        int pn = __popcll(mn & below);
        int bp = 0, bn = 0;
        if (lane == 0) {
            if (np) bp = atomicAdd(&cnts[0], np);
            if (nn) bn = atomicAdd(&cnts[1], nn);
        }
        bp = __shfl(bp, 0);
        bn = __shfl(bn, 0);
        if (pos) list[bp + pp] = e;
        if (neg) list[NEDGES - 1 - (bn + pn)] = e;
    }
}

__device__ __forceinline__ unsigned int pk16(_Float16 a, _Float16 b) {
    return (unsigned int)__builtin_bit_cast(unsigned short, a) |
           ((unsigned int)__builtin_bit_cast(unsigned short, b) << 16);
}

// store one M-tile of activations (f32x4 per lane) as hi/lo f16 into swizzled LDS
__device__ __forceinline__ void trans_store(unsigned int* hb, int n, int rb, int mt, f32x4 v)
{
    _Float16 h0 = (_Float16)v[0], h1 = (_Float16)v[1], h2 = (_Float16)v[2], h3 = (_Float16)v[3];
    float r0 = v[0] - (float)h0, r1 = v[1] - (float)h1, r2 = v[2] - (float)h2, r3 = v[3] - (float)h3;
    unsigned int hd0 = pk16(h0, h1), hd1 = pk16(h2, h3);
    unsigned int ld0 = pk16((_Float16)r0, (_Float16)r1), ld1 = pk16((_Float16)r2, (_Float16)r3);
    const int b  = 2 * mt + (rb >> 1);
    const int bp = b ^ (n & 7);
    const int dw = n * 32 + (bp << 2) + ((rb & 1) << 1);
    *reinterpret_cast<uint2*>(hb + dw)       = make_uint2(hd0, hd1);
    *reinterpret_cast<uint2*>(hb + 512 + dw) = make_uint2(ld0, ld1);
}

__device__ __forceinline__ f16x8 read_b(const unsigned int* hb, int n, int kb, int kt, int lobuf)
{
    const int b  = kt * 4 + kb;
    const int bp = b ^ (n & 7);
    uint4 d = *reinterpret_cast<const uint4*>(hb + lobuf * 512 + n * 32 + (bp << 2));
    return __builtin_bit_cast(f16x8, d);
}

#define MF(acc, WH, WL, BH, BL)                                                    \
    acc = __builtin_amdgcn_mfma_f32_16x16x32_f16(WH, BH, acc, 0, 0, 0);            \
    acc = __builtin_amdgcn_mfma_f32_16x16x32_f16(WH, BL, acc, 0, 0, 0);            \
    acc = __builtin_amdgcn_mfma_f32_16x16x32_f16(WL, BH, acc, 0, 0, 0);

// relu 3 tiles, set bias-one (m=35), store to LDS
#define TRANSITION(X0, X1, X2)                                                     \
    {                                                                              \
        _Pragma("unroll")                                                          \
        for (int r = 0; r < 4; ++r) {                                              \
            X0[r] = fmaxf(X0[r], 0.0f);                                            \
            X1[r] = fmaxf(X1[r], 0.0f);                                            \
            X2[r] = fmaxf(X2[r], 0.0f);                                            \
        }                                                                          \
        if (kb == 0) X2[3] = 1.0f;                                                 \
        trans_store(hb, n, kb, 0, X0);                                             \
        trans_store(hb, n, kb, 1, X1);                                             \
        trans_store(hb, n, kb, 2, X2);                                             \
    }

#define HLAYER(U0, C0, C1, C2)                                                     \
    {                                                                              \
        f16x8 bh0 = read_b(hb, n, kb, 0, 0), bl0 = read_b(hb, n, kb, 0, 1);        \
        f16x8 bh1 = read_b(hb, n, kb, 1, 0), bl1 = read_b(hb, n, kb, 1, 1);        \
        C0 = z4; C1 = z4; C2 = z4;                                                 \
        __builtin_amdgcn_s_setprio(1);                                             \
        MF(C0, wh[(U0) + 0], wl[(U0) + 0], bh0, bl0)                               \
        MF(C0, wh[(U0) + 1], wl[(U0) + 1], bh1, bl1)                               \
        MF(C1, wh[(U0) + 2], wl[(U0) + 2], bh0, bl0)                               \
        MF(C1, wh[(U0) + 3], wl[(U0) + 3], bh1, bl1)                               \
        MF(C2, wh[(U0) + 4], wl[(U0) + 4], bh0, bl0)                               \
        MF(C2, wh[(U0) + 5], wl[(U0) + 5], bh1, bl1)                               \
        __builtin_amdgcn_s_setprio(0);                                             \
    }

__global__ void __launch_bounds__(256, 2) edge_kernel(
    const float* __restrict__ score,
    const int*   __restrict__ edge_idx,
    const unsigned short* __restrict__ frags,
    const int*   __restrict__ list,
    const int*   __restrict__ cnts,
    float* __restrict__ agg, int* __restrict__ deg)
{
    __shared__ unsigned int hbuf[4][1024];
    const int tid  = threadIdx.x;
    const int wv   = tid >> 6;
    const int lane = tid & 63;
    const int n    = lane & 15;
    const int kb   = lane >> 4;
    const int k0   = kb * 8;
    unsigned int* hb = &hbuf[wv][0];

    for (int i = lane; i < 1024; i += 64) hb[i] = 0;   // zero pad region (intra-wave)

    const int gw    = blockIdx.x * 4 + wv;
    const int combo = gw & 3;
    const int wci   = gw >> 2;

    const int cp   = cnts[0];
    const int useR = (combo < 2);
    const int rev  = (combo == 1 || combo == 2);
    const float sgn = useR ? 1.0f : -1.0f;
    const int lo_  = (combo == 0 || combo == 2) ? 0 : cp;
    const int hi_  = (combo == 0 || combo == 2) ? cp : NEDGES;
    const int cnt  = hi_ - lo_;
    const int revoff = rev ? 5 : 0;
    const int t0   = useR ? 0 : NTILES_PER_NET;

    // resident weight fragments
    f16x8 wh[18], wl[18];
    #pragma unroll
    for (int u = 0; u < 18; ++u) {
        const int t = t0 + 6 + u;
        wh[u] = *reinterpret_cast<const f16x8*>(frags + ((size_t)(t * 2 + 0) * 64 + lane) * 8);
        wl[u] = *reinterpret_cast<const f16x8*>(frags + ((size_t)(t * 2 + 1) * 64 + lane) * 8);
    }
    f16x8 w0h[3], w0l[3], w4h[2], w4l[2];
    #pragma unroll
    for (int mt = 0; mt < 3; ++mt) {
        const int t = t0 + (rev ? 3 : 0) + mt;
        w0h[mt] = *reinterpret_cast<const f16x8*>(frags + ((size_t)(t * 2 + 0) * 64 + lane) * 8);
        w0l[mt] = *reinterpret_cast<const f16x8*>(frags + ((size_t)(t * 2 + 1) * 64 + lane) * 8);
    }
    #pragma unroll
    for (int kt = 0; kt < 2; ++kt) {
        const int t = t0 + 24 + kt;
        w4h[kt] = *reinterpret_cast<const f16x8*>(frags + ((size_t)(t * 2 + 0) * 64 + lane) * 8);
        w4l[kt] = *reinterpret_cast<const f16x8*>(frags + ((size_t)(t * 2 + 1) * 64 + lane) * 8);
    }

    const f32x4 z4 = {0.0f, 0.0f, 0.0f, 0.0f};

    // gather of one 16-edge pass: list -> edge_idx -> score chain
    auto GATHER = [&](int b, float (&s)[8], int& edo, bool& ao) {
        ao  = (b + n) < cnt;
        edo = list[ao ? (lo_ + b + n) : lo_];
        #pragma unroll
        for (int j = 0; j < 8; ++j) {
            const int k = k0 + j;
            const int id = (k < 10) ? edge_idx[edo * 10 + k] : 0;
            s[j] = (k < 10) ? score[id] : 0.0f;
        }
        if (kb == 1) s[2] = 1.0f;   // bias-one at k=10
    };

    int   base = wci * 16;
    float sc[8];
    int   ecur = 0;
    bool  act  = false;
    if (base < cnt) GATHER(base, sc, ecur, act);

    #pragma unroll 1
    for (; base < cnt; ) {
        const int nbase = base + (int)gridDim.x * 16;
        float scn[8];
        int   enx  = 0;
        bool  actn = false;
        if (nbase < cnt) GATHER(nbase, scn, enx, actn);   // prefetch next pass

        f16x8 bxh, bxl;
        #pragma unroll
        for (int j = 0; j < 8; ++j) {
            _Float16 h = (_Float16)sc[j];
            bxh[j] = h;
            bxl[j] = (_Float16)(sc[j] - (float)h);
        }

        // L0
        f32x4 a0 = z4, a1 = z4, a2 = z4;
        __builtin_amdgcn_s_setprio(1);
        MF(a0, w0h[0], w0l[0], bxh, bxl)
        MF(a1, w0h[1], w0l[1], bxh, bxl)
        MF(a2, w0h[2], w0l[2], bxh, bxl)
        __builtin_amdgcn_s_setprio(0);
        TRANSITION(a0, a1, a2)

        f32x4 c0, c1, c2;
        HLAYER(0, c0, c1, c2)
        TRANSITION(c0, c1, c2)
        HLAYER(6, c0, c1, c2)
        TRANSITION(c0, c1, c2)
        HLAYER(12, c0, c1, c2)
        TRANSITION(c0, c1, c2)

        // L4
        f32x4 c4 = z4;
        {
            f16x8 bh0 = read_b(hb, n, kb, 0, 0), bl0 = read_b(hb, n, kb, 0, 1);
            f16x8 bh1 = read_b(hb, n, kb, 1, 0), bl1 = read_b(hb, n, kb, 1, 1);
            __builtin_amdgcn_s_setprio(1);
            MF(c4, w4h[0], w4l[0], bh0, bl0)
            MF(c4, w4h[1], w4l[1], bh1, bl1)
            __builtin_amdgcn_s_setprio(0);
        }

        // sigmoid + signed scatter + degree count: out row q = kb*4 + r (q < 5)
        #pragma unroll
        for (int r = 0; r < 4; ++r) {
            const int q = kb * 4 + r;
            if (act && q < 5) {
                const float v = sgn / (1.0f + __expf(-c4[r]));
                const int tgt = edge_idx[ecur * 10 + revoff + q];
                unsafeAtomicAdd(&agg[tgt], v);
                atomicAdd(&deg[tgt], 1);
            }
        }

        base = nbase;
        #pragma unroll
        for (int j = 0; j < 8; ++j) sc[j] = scn[j];
        ecur = enx;
        act  = actn;
    }
}

__global__ void __launch_bounds__(256) degmax_kernel(const int* __restrict__ deg,
                                                     int* __restrict__ degmax)
{
    int m = 0;
    for (int i = blockIdx.x * blockDim.x + threadIdx.x; i < NNODES;
         i += gridDim.x * blockDim.x)
        m = max(m, deg[i]);
    #pragma unroll
    for (int off = 32; off; off >>= 1) m = max(m, __shfl_down(m, off));
    __shared__ int sm[4];
    if ((threadIdx.x & 63) == 0) sm[threadIdx.x >> 6] = m;
    __syncthreads();
    if (threadIdx.x == 0) {
        int mm = sm[0];
        #pragma unroll
        for (int w = 1; w < 4; ++w) mm = max(mm, sm[w]);
        atomicMax(degmax, mm);
    }
}

__global__ void __launch_bounds__(256) stats_kernel(const float* __restrict__ score,
                                                    const float* __restrict__ agg,
                                                    const int* __restrict__ degmax,
                                                    float* __restrict__ stats)
{
    const float scale = 2.0f / (float)(*degmax);
    float s = 0.0f, s2 = 0.0f;
    for (int i = blockIdx.x * blockDim.x + threadIdx.x; i < NNODES;
         i += gridDim.x * blockDim.x) {
        float v = fmaf(agg[i], scale, score[i]);
        s += v;
        s2 = fmaf(v, v, s2);
    }
    #pragma unroll
    for (int off = 32; off; off >>= 1) {
        s  += __shfl_down(s, off);
        s2 += __shfl_down(s2, off);
    }
    __shared__ float ssum[4], ssq[4];
    if ((threadIdx.x & 63) == 0) { ssum[threadIdx.x >> 6] = s; ssq[threadIdx.x >> 6] = s2; }
    __syncthreads();
    if (threadIdx.x == 0) {
        float a = 0.0f, b = 0.0f;
        #pragma unroll
        for (int w = 0; w < 4; ++w) { a += ssum[w]; b += ssq[w]; }
        unsafeAtomicAdd(&stats[0], a);
        unsafeAtomicAdd(&stats[1], b);
    }
}

__global__ void __launch_bounds__(256) finalize_kernel(const float* __restrict__ score,
                                                       const float* __restrict__ agg,
                                                       const int* __restrict__ degmax,
                                                       const float* __restrict__ stats,
                                                       float* __restrict__ out)
{
    const float scale = 2.0f / (float)(*degmax);
    const float sum = stats[0], sumsq = stats[1];
    const float mean = sum * (1.0f / NNODES);
    const float rn = 1.0f / sqrtf(sumsq - sum * mean);
    for (int i = blockIdx.x * blockDim.x + threadIdx.x; i < NNODES;
         i += gridDim.x * blockDim.x) {
        float v = fmaf(agg[i], scale, score[i]);
        out[i] = (v - mean) * rn;
    }
}

extern "C" void kernel_launch(void* const* d_in, const int* in_sizes, int n_in,
                              void* d_out, int out_size, void* d_ws, size_t ws_size,
                              hipStream_t stream)
{
    const float* score    = (const float*)d_in[0];
    const int*   edge_idx = (const int*)  d_in[1];
    const float* outcome  = (const float*)d_in[2];
    const float* Rsw = (const float*)d_in[3];
    const float* Rsb = (const float*)d_in[4];
    const float* Rhw = (const float*)d_in[5];
    const float* Rhb = (const float*)d_in[6];
    const float* Rew = (const float*)d_in[7];
    const float* Reb = (const float*)d_in[8];
    const float* Psw = (const float*)d_in[9];
    const float* Psb = (const float*)d_in[10];
    const float* Phw = (const float*)d_in[11];
    const float* Phb = (const float*)d_in[12];
    const float* Pew = (const float*)d_in[13];
    const float* Peb = (const float*)d_in[14];
    float* out = (float*)d_out;

    char* ws = (char*)d_ws;
    float*          agg    = (float*)(ws + WS_AGG);
    int*            deg    = (int*)  (ws + WS_DEG);
    float*          stats  = (float*)(ws + WS_STATS);
    int*            degmax = (int*)  (ws + WS_DEGMAX);
    int*            cnts   = (int*)  (ws + WS_CNTS);
    unsigned short* frags  = (unsigned short*)(ws + WS_FRAGS);
    int*            list   = (int*)  (ws + WS_LIST);

    hipMemsetAsync(d_ws, 0, WS_ZERO_BYTES, stream);

    prep_frag_kernel<<<52, 64, 0, stream>>>(Rsw, Rsb, Rhw, Rhb, Rew, Reb,
                                            Psw, Psb, Phw, Phb, Pew, Peb, frags);
    sort_kernel<<<1024, 256, 0, stream>>>(outcome, list, cnts);

    edge_kernel<<<2048, 256, 0, stream>>>(score, edge_idx, frags, list, cnts, agg, deg);

    const int nb = (NNODES + 255) / 256;
    degmax_kernel  <<<nb, 256, 0, stream>>>(deg, degmax);
    stats_kernel   <<<nb, 256, 0, stream>>>(score, agg, degmax, stats);
    finalize_kernel<<<nb, 256, 0, stream>>>(score, agg, degmax, stats, out);
}

// Round 5
// 662.506 us; speedup vs baseline: 2.8019x; 2.0648x over previous
//
#include <hip/hip_runtime.h>
#include <hip/hip_bf16.h>
#include <hip/hip_fp16.h>

typedef _Float16 f16x8 __attribute__((ext_vector_type(8)));
typedef float    f32x4 __attribute__((ext_vector_type(4)));

#define NNODES 100000
#define NEDGES 1000000

// deg packed into f64 atomic: contribution = val + 2^20
#define PK_SCALE   1048576.0
#define PK_INV     9.5367431640625e-07

// ---- workspace layout (bytes) ----
#define WS_AGGD   0u          // double[N]  (800000 B)
#define WS_STATS  800000u     // float[2]
#define WS_DEGMAX 800008u     // int
#define WS_CNTS   800012u     // int[2]
#define WS_ZERO_BYTES 800020u
#define WS_FRAGS  800032u     // ushort[52][2][64][8]  (106496 B, 16B aligned)
#define WS_LIST   906528u     // int[E]

// tiles per net: 0-2 L0 fwd mt, 3-5 L0 rev mt, 6-23 L1-3 [(L-1)*6 + mt*2 + kt], 24-25 L4 kt
#define NTILES_PER_NET 26

__global__ void __launch_bounds__(64) prep_frag_kernel(
    const float* __restrict__ Rsw, const float* __restrict__ Rsb,
    const float* __restrict__ Rhw, const float* __restrict__ Rhb,
    const float* __restrict__ Rew, const float* __restrict__ Reb,
    const float* __restrict__ Psw, const float* __restrict__ Psb,
    const float* __restrict__ Phw, const float* __restrict__ Phb,
    const float* __restrict__ Pew, const float* __restrict__ Peb,
    unsigned short* __restrict__ frags)
{
    const int t = blockIdx.x;          // 0..51
    const int l = threadIdx.x;         // 0..63
    const int net = t / NTILES_PER_NET;
    const int tt  = t % NTILES_PER_NET;
    const float *sw, *sb, *hw, *hb, *ew, *eb;
    if (net == 0) { sw=Rsw; sb=Rsb; hw=Rhw; hb=Rhb; ew=Rew; eb=Reb; }
    else          { sw=Psw; sb=Psb; hw=Phw; hb=Phb; ew=Pew; eb=Peb; }

    int layer, mt, kt = 0, rev = 0;
    if (tt < 6)       { layer = 0; rev = (tt >= 3); mt = tt % 3; }
    else if (tt < 24) { int u = tt - 6; layer = 1 + u / 6; u %= 6; mt = u / 2; kt = u % 2; }
    else              { layer = 4; mt = 0; kt = tt - 24; }

    const int m     = mt * 16 + (l & 15);
    const int kbase = kt * 32 + (l >> 4) * 8;

    unsigned short hi8[8], lo8[8];
    #pragma unroll
    for (int j = 0; j < 8; ++j) {
        const int k = kbase + j;
        float v = 0.0f;
        if (layer == 0) {
            if (m < 35) { if (k < 10) v = sw[m * 10 + (rev ? 9 - k : k)];
                          else if (k == 10) v = sb[m]; }
        } else if (layer <= 3) {
            if (m < 35) { if (k < 35) v = hw[(layer - 1) * 1225 + m * 35 + k];
                          else if (k == 35) v = hb[(layer - 1) * 35 + m]; }
        } else {
            if (m < 5)  { if (k < 35) v = ew[m * 35 + k];
                          else if (k == 35) v = eb[m]; }
        }
        _Float16 h = (_Float16)v;
        _Float16 lo = (_Float16)(v - (float)h);
        hi8[j] = __builtin_bit_cast(unsigned short, h);
        lo8[j] = __builtin_bit_cast(unsigned short, lo);
    }
    unsigned short* bh = frags + ((size_t)(t * 2 + 0) * 64 + l) * 8;
    unsigned short* bl = frags + ((size_t)(t * 2 + 1) * 64 + l) * 8;
    #pragma unroll
    for (int j = 0; j < 8; ++j) { bh[j] = hi8[j]; bl[j] = lo8[j]; }
}

// block-aggregated two-ended compaction by outcome sign (2 atomics per block-iter)
__global__ void __launch_bounds__(256) sort_kernel(
    const float* __restrict__ outcome, int* __restrict__ list, int* __restrict__ cnts)
{
    __shared__ int wTotP[4], wTotN[4], wBaseP[4], wBaseN[4], blkP, blkN;
    const int tid = threadIdx.x, wv = tid >> 6, lane = tid & 63;

    #pragma unroll 1
    for (int start = blockIdx.x * 2048; start < NEDGES; start += gridDim.x * 2048) {
        const int e0 = start + tid * 8;
        int valid[8], isp[8];
        int pc = 0, nc = 0;
        #pragma unroll
        for (int j = 0; j < 8; ++j) {
            const int e = e0 + j;
            valid[j] = (e < NEDGES);
            float o = valid[j] ? outcome[e] : 0.0f;
            isp[j] = valid[j] && (o > 0.0f);
            pc += isp[j];
            nc += (valid[j] && !isp[j]);
        }
        // wave inclusive scan of pc/nc
        int pi = pc, ni = nc;
        #pragma unroll
        for (int off = 1; off < 64; off <<= 1) {
            int tp = __shfl_up(pi, off);
            int tn = __shfl_up(ni, off);
            if (lane >= off) { pi += tp; ni += tn; }
        }
        const int pex = pi - pc, nex = ni - nc;
        if (lane == 63) { wTotP[wv] = pi; wTotN[wv] = ni; }
        __syncthreads();
        if (tid == 0) {
            int tp = 0, tn = 0;
            #pragma unroll
            for (int w = 0; w < 4; ++w) {
                wBaseP[w] = tp; wBaseN[w] = tn;
                tp += wTotP[w]; tn += wTotN[w];
            }
            blkP = atomicAdd(&cnts[0], tp);
            blkN = atomicAdd(&cnts[1], tn);
        }
        __syncthreads();
        int pbase = blkP + wBaseP[wv] + pex;
        int nbase = blkN + wBaseN[wv] + nex;
        #pragma unroll
        for (int j = 0; j < 8; ++j) {
            if (isp[j])        list[pbase++] = e0 + j;
            else if (valid[j]) list[NEDGES - 1 - (nbase++)] = e0 + j;
        }
        __syncthreads();
    }
}

__device__ __forceinline__ unsigned int pk16(_Float16 a, _Float16 b) {
    return (unsigned int)__builtin_bit_cast(unsigned short, a) |
           ((unsigned int)__builtin_bit_cast(unsigned short, b) << 16);
}

// store one M-tile of activations (f32x4 per lane) as hi/lo f16 into swizzled LDS
__device__ __forceinline__ void trans_store(unsigned int* hb, int n, int rb, int mt, f32x4 v)
{
    _Float16 h0 = (_Float16)v[0], h1 = (_Float16)v[1], h2 = (_Float16)v[2], h3 = (_Float16)v[3];
    float r0 = v[0] - (float)h0, r1 = v[1] - (float)h1, r2 = v[2] - (float)h2, r3 = v[3] - (float)h3;
    unsigned int hd0 = pk16(h0, h1), hd1 = pk16(h2, h3);
    unsigned int ld0 = pk16((_Float16)r0, (_Float16)r1), ld1 = pk16((_Float16)r2, (_Float16)r3);
    const int b  = 2 * mt + (rb >> 1);
    const int bp = b ^ (n & 7);
    const int dw = n * 32 + (bp << 2) + ((rb & 1) << 1);
    *reinterpret_cast<uint2*>(hb + dw)       = make_uint2(hd0, hd1);
    *reinterpret_cast<uint2*>(hb + 512 + dw) = make_uint2(ld0, ld1);
}

__device__ __forceinline__ f16x8 read_b(const unsigned int* hb, int n, int kb, int kt, int lobuf)
{
    const int b  = kt * 4 + kb;
    const int bp = b ^ (n & 7);
    uint4 d = *reinterpret_cast<const uint4*>(hb + lobuf * 512 + n * 32 + (bp << 2));
    return __builtin_bit_cast(f16x8, d);
}

#define MF(acc, WH, WL, BH, BL)                                                    \
    acc = __builtin_amdgcn_mfma_f32_16x16x32_f16(WH, BH, acc, 0, 0, 0);            \
    acc = __builtin_amdgcn_mfma_f32_16x16x32_f16(WH, BL, acc, 0, 0, 0);            \
    acc = __builtin_amdgcn_mfma_f32_16x16x32_f16(WL, BH, acc, 0, 0, 0);

// relu 3 tiles, set bias-one (m=35), store to LDS
#define TRANSITION(X0, X1, X2)                                                     \
    {                                                                              \
        _Pragma("unroll")                                                          \
        for (int r = 0; r < 4; ++r) {                                              \
            X0[r] = fmaxf(X0[r], 0.0f);                                            \
            X1[r] = fmaxf(X1[r], 0.0f);                                            \
            X2[r] = fmaxf(X2[r], 0.0f);                                            \
        }                                                                          \
        if (kb == 0) X2[3] = 1.0f;                                                 \
        trans_store(hb, n, kb, 0, X0);                                             \
        trans_store(hb, n, kb, 1, X1);                                             \
        trans_store(hb, n, kb, 2, X2);                                             \
    }

#define HLAYER(U0, C0, C1, C2)                                                     \
    {                                                                              \
        f16x8 bh0 = read_b(hb, n, kb, 0, 0), bl0 = read_b(hb, n, kb, 0, 1);        \
        f16x8 bh1 = read_b(hb, n, kb, 1, 0), bl1 = read_b(hb, n, kb, 1, 1);        \
        C0 = z4; C1 = z4; C2 = z4;                                                 \
        __builtin_amdgcn_s_setprio(1);                                             \
        MF(C0, wh[(U0) + 0], wl[(U0) + 0], bh0, bl0)                               \
        MF(C0, wh[(U0) + 1], wl[(U0) + 1], bh1, bl1)                               \
        MF(C1, wh[(U0) + 2], wl[(U0) + 2], bh0, bl0)                               \
        MF(C1, wh[(U0) + 3], wl[(U0) + 3], bh1, bl1)                               \
        MF(C2, wh[(U0) + 4], wl[(U0) + 4], bh0, bl0)                               \
        MF(C2, wh[(U0) + 5], wl[(U0) + 5], bh1, bl1)                               \
        __builtin_amdgcn_s_setprio(0);                                             \
    }

__global__ void __launch_bounds__(256, 2) edge_kernel(
    const float* __restrict__ score,
    const int*   __restrict__ edge_idx,
    const unsigned short* __restrict__ frags,
    const int*   __restrict__ list,
    const int*   __restrict__ cnts,
    double* __restrict__ aggd)
{
    __shared__ unsigned int hbuf[4][1024];
    const int tid  = threadIdx.x;
    const int wv   = tid >> 6;
    const int lane = tid & 63;
    const int n    = lane & 15;
    const int kb   = lane >> 4;
    const int k0   = kb * 8;
    unsigned int* hb = &hbuf[wv][0];

    for (int i = lane; i < 1024; i += 64) hb[i] = 0;   // zero pad region (intra-wave)

    const int gw    = blockIdx.x * 4 + wv;
    const int combo = gw & 3;
    const int wci   = gw >> 2;

    const int cp   = cnts[0];
    const int useR = (combo < 2);
    const int rev  = (combo == 1 || combo == 2);
    const float sgn = useR ? 1.0f : -1.0f;
    const int lo_  = (combo == 0 || combo == 2) ? 0 : cp;
    const int hi_  = (combo == 0 || combo == 2) ? cp : NEDGES;
    const int cnt  = hi_ - lo_;
    const int revoff = rev ? 5 : 0;
    const int t0   = useR ? 0 : NTILES_PER_NET;

    // resident weight fragments
    f16x8 wh[18], wl[18];
    #pragma unroll
    for (int u = 0; u < 18; ++u) {
        const int t = t0 + 6 + u;
        wh[u] = *reinterpret_cast<const f16x8*>(frags + ((size_t)(t * 2 + 0) * 64 + lane) * 8);
        wl[u] = *reinterpret_cast<const f16x8*>(frags + ((size_t)(t * 2 + 1) * 64 + lane) * 8);
    }
    f16x8 w0h[3], w0l[3], w4h[2], w4l[2];
    #pragma unroll
    for (int mt = 0; mt < 3; ++mt) {
        const int t = t0 + (rev ? 3 : 0) + mt;
        w0h[mt] = *reinterpret_cast<const f16x8*>(frags + ((size_t)(t * 2 + 0) * 64 + lane) * 8);
        w0l[mt] = *reinterpret_cast<const f16x8*>(frags + ((size_t)(t * 2 + 1) * 64 + lane) * 8);
    }
    #pragma unroll
    for (int kt = 0; kt < 2; ++kt) {
        const int t = t0 + 24 + kt;
        w4h[kt] = *reinterpret_cast<const f16x8*>(frags + ((size_t)(t * 2 + 0) * 64 + lane) * 8);
        w4l[kt] = *reinterpret_cast<const f16x8*>(frags + ((size_t)(t * 2 + 1) * 64 + lane) * 8);
    }

    const f32x4 z4 = {0.0f, 0.0f, 0.0f, 0.0f};

    // gather of one 16-edge pass: list -> edge_idx -> score chain
    auto GATHER = [&](int b, float (&s)[8], int& edo, bool& ao) {
        ao  = (b + n) < cnt;
        edo = list[ao ? (lo_ + b + n) : lo_];
        #pragma unroll
        for (int j = 0; j < 8; ++j) {
            const int k = k0 + j;
            const int id = (k < 10) ? edge_idx[edo * 10 + k] : 0;
            s[j] = (k < 10) ? score[id] : 0.0f;
        }
        if (kb == 1) s[2] = 1.0f;   // bias-one at k=10
    };

    int   base = wci * 16;
    float sc[8];
    int   ecur = 0;
    bool  act  = false;
    if (base < cnt) GATHER(base, sc, ecur, act);

    #pragma unroll 1
    for (; base < cnt; ) {
        const int nbase = base + (int)gridDim.x * 16;
        float scn[8];
        int   enx  = 0;
        bool  actn = false;
        if (nbase < cnt) GATHER(nbase, scn, enx, actn);   // prefetch next pass

        f16x8 bxh, bxl;
        #pragma unroll
        for (int j = 0; j < 8; ++j) {
            _Float16 h = (_Float16)sc[j];
            bxh[j] = h;
            bxl[j] = (_Float16)(sc[j] - (float)h);
        }

        // L0
        f32x4 a0 = z4, a1 = z4, a2 = z4;
        __builtin_amdgcn_s_setprio(1);
        MF(a0, w0h[0], w0l[0], bxh, bxl)
        MF(a1, w0h[1], w0l[1], bxh, bxl)
        MF(a2, w0h[2], w0l[2], bxh, bxl)
        __builtin_amdgcn_s_setprio(0);
        TRANSITION(a0, a1, a2)

        f32x4 c0, c1, c2;
        HLAYER(0, c0, c1, c2)
        TRANSITION(c0, c1, c2)
        HLAYER(6, c0, c1, c2)
        TRANSITION(c0, c1, c2)
        HLAYER(12, c0, c1, c2)
        TRANSITION(c0, c1, c2)

        // L4
        f32x4 c4 = z4;
        {
            f16x8 bh0 = read_b(hb, n, kb, 0, 0), bl0 = read_b(hb, n, kb, 0, 1);
            f16x8 bh1 = read_b(hb, n, kb, 1, 0), bl1 = read_b(hb, n, kb, 1, 1);
            __builtin_amdgcn_s_setprio(1);
            MF(c4, w4h[0], w4l[0], bh0, bl0)
            MF(c4, w4h[1], w4l[1], bh1, bl1)
            __builtin_amdgcn_s_setprio(0);
        }

        // sigmoid + signed scatter + packed degree: one f64 atomic per slot
        #pragma unroll
        for (int r = 0; r < 4; ++r) {
            const int q = kb * 4 + r;
            if (act && q < 5) {
                const float v = sgn / (1.0f + __expf(-c4[r]));
                const int tgt = edge_idx[ecur * 10 + revoff + q];
                unsafeAtomicAdd(&aggd[tgt], (double)v + PK_SCALE);
            }
        }

        base = nbase;
        #pragma unroll
        for (int j = 0; j < 8; ++j) sc[j] = scn[j];
        ecur = enx;
        act  = actn;
    }
}

__global__ void __launch_bounds__(256) degmax_kernel(const double* __restrict__ aggd,
                                                     int* __restrict__ degmax)
{
    int m = 0;
    for (int i = blockIdx.x * blockDim.x + threadIdx.x; i < NNODES;
         i += gridDim.x * blockDim.x)
        m = max(m, (int)(aggd[i] * PK_INV + 0.5));
    #pragma unroll
    for (int off = 32; off; off >>= 1) m = max(m, __shfl_down(m, off));
    __shared__ int sm[4];
    if ((threadIdx.x & 63) == 0) sm[threadIdx.x >> 6] = m;
    __syncthreads();
    if (threadIdx.x == 0) {
        int mm = sm[0];
        #pragma unroll
        for (int w = 1; w < 4; ++w) mm = max(mm, sm[w]);
        atomicMax(degmax, mm);
    }
}

__global__ void __launch_bounds__(256) stats_kernel(const float* __restrict__ score,
                                                    const double* __restrict__ aggd,
                                                    const int* __restrict__ degmax,
                                                    float* __restrict__ stats)
{
    const float scale = 2.0f / (float)(*degmax);
    float s = 0.0f, s2 = 0.0f;
    for (int i = blockIdx.x * blockDim.x + threadIdx.x; i < NNODES;
         i += gridDim.x * blockDim.x) {
        const double T = aggd[i];
        const int d = (int)(T * PK_INV + 0.5);
        const float vs = (float)(T - (double)d * PK_SCALE);
        float v = fmaf(vs, scale, score[i]);
        s += v;
        s2 = fmaf(v, v, s2);
    }
    #pragma unroll
    for (int off = 32; off; off >>= 1) {
        s  += __shfl_down(s, off);
        s2 += __shfl_down(s2, off);
    }
    __shared__ float ssum[4], ssq[4];
    if ((threadIdx.x & 63) == 0) { ssum[threadIdx.x >> 6] = s; ssq[threadIdx.x >> 6] = s2; }
    __syncthreads();
    if (threadIdx.x == 0) {
        float a = 0.0f, b = 0.0f;
        #pragma unroll
        for (int w = 0; w < 4; ++w) { a += ssum[w]; b += ssq[w]; }
        unsafeAtomicAdd(&stats[0], a);
        unsafeAtomicAdd(&stats[1], b);
    }
}

__global__ void __launch_bounds__(256) finalize_kernel(const float* __restrict__ score,
                                                       const double* __restrict__ aggd,
                                                       const int* __restrict__ degmax,
                                                       const float* __restrict__ stats,
                                                       float* __restrict__ out)
{
    const float scale = 2.0f / (float)(*degmax);
    const float sum = stats[0], sumsq = stats[1];
    const float mean = sum * (1.0f / NNODES);
    const float rn = 1.0f / sqrtf(sumsq - sum * mean);
    for (int i = blockIdx.x * blockDim.x + threadIdx.x; i < NNODES;
         i += gridDim.x * blockDim.x) {
        const double T = aggd[i];
        const int d = (int)(T * PK_INV + 0.5);
        const float vs = (float)(T - (double)d * PK_SCALE);
        float v = fmaf(vs, scale, score[i]);
        out[i] = (v - mean) * rn;
    }
}

extern "C" void kernel_launch(void* const* d_in, const int* in_sizes, int n_in,
                              void* d_out, int out_size, void* d_ws, size_t ws_size,
                              hipStream_t stream)
{
    const float* score    = (const float*)d_in[0];
    const int*   edge_idx = (const int*)  d_in[1];
    const float* outcome  = (const float*)d_in[2];
    const float* Rsw = (const float*)d_in[3];
    const float* Rsb = (const float*)d_in[4];
    const float* Rhw = (const float*)d_in[5];
    const float* Rhb = (const float*)d_in[6];
    const float* Rew = (const float*)d_in[7];
    const float* Reb = (const float*)d_in[8];
    const float* Psw = (const float*)d_in[9];
    const float* Psb = (const float*)d_in[10];
    const float* Phw = (const float*)d_in[11];
    const float* Phb = (const float*)d_in[12];
    const float* Pew = (const float*)d_in[13];
    const float* Peb = (const float*)d_in[14];
    float* out = (float*)d_out;

    char* ws = (char*)d_ws;
    double*         aggd   = (double*)(ws + WS_AGGD);
    float*          stats  = (float*)(ws + WS_STATS);
    int*            degmax = (int*)  (ws + WS_DEGMAX);
    int*            cnts   = (int*)  (ws + WS_CNTS);
    unsigned short* frags  = (unsigned short*)(ws + WS_FRAGS);
    int*            list   = (int*)  (ws + WS_LIST);

    hipMemsetAsync(d_ws, 0, WS_ZERO_BYTES, stream);

    prep_frag_kernel<<<52, 64, 0, stream>>>(Rsw, Rsb, Rhw, Rhb, Rew, Reb,
                                            Psw, Psb, Phw, Phb, Pew, Peb, frags);
    sort_kernel<<<256, 256, 0, stream>>>(outcome, list, cnts);

    edge_kernel<<<2048, 256, 0, stream>>>(score, edge_idx, frags, list, cnts, aggd);

    const int nb = (NNODES + 255) / 256;
    degmax_kernel  <<<nb, 256, 0, stream>>>(aggd, degmax);
    stats_kernel   <<<nb, 256, 0, stream>>>(score, aggd, degmax, stats);
    finalize_kernel<<<nb, 256, 0, stream>>>(score, aggd, degmax, stats, out);
}

// Round 7
// 603.765 us; speedup vs baseline: 3.0746x; 1.0973x over previous
//
#include <hip/hip_runtime.h>
#include <hip/hip_bf16.h>
#include <hip/hip_fp16.h>

typedef _Float16 f16x8 __attribute__((ext_vector_type(8)));
typedef float    f32x4 __attribute__((ext_vector_type(4)));

#define NNODES 100000
#define NEDGES 1000000
#define NREC   10000000ll

// fallback f64 packing
#define PK_SCALE   1048576.0
#define PK_INV     9.5367431640625e-07

// ---- workspace layout (bytes) ----
#define WS_AGG    0u          // fast: f32[N] ; fallback: aggd f64[N] occupies 0..800000
#define WS_DEG    400000u     // fast: int[N]
#define WS_STATS  800000u
#define WS_DEGMAX 800008u
#define WS_CNTS   800012u
#define WS_ZERO_END 800020u
#define WS_FRAGS  800032u     // 106496 B
#define WS_LIST   906528u     // int[E] -> ends 4906528
#define WS_BASE   4906528u    // u32[257]
#define WS_COLT   4907584u    // u32[256]
#define WS_HIST   4908608u    // u32[2048*256] = 2097152
#define WS_OFFS   7005760u    // u32[2048*256]
#define WS_RECS   9102912u    // u64[1e7] = 80 MB
#define WS_BINN   89102912u   // u64[1e7]
#define WS_NEED   169102912u

#define S3_BLOCKS 2048
#define S3_CHUNK  4883ll      // ceil(1e7/2048)

#define NTILES_PER_NET 26

__global__ void __launch_bounds__(64) prep_frag_kernel(
    const float* __restrict__ Rsw, const float* __restrict__ Rsb,
    const float* __restrict__ Rhw, const float* __restrict__ Rhb,
    const float* __restrict__ Rew, const float* __restrict__ Reb,
    const float* __restrict__ Psw, const float* __restrict__ Psb,
    const float* __restrict__ Phw, const float* __restrict__ Phb,
    const float* __restrict__ Pew, const float* __restrict__ Peb,
    unsigned short* __restrict__ frags)
{
    const int t = blockIdx.x;          // 0..51
    const int l = threadIdx.x;         // 0..63
    const int net = t / NTILES_PER_NET;
    const int tt  = t % NTILES_PER_NET;
    const float *sw, *sb, *hw, *hb, *ew, *eb;
    if (net == 0) { sw=Rsw; sb=Rsb; hw=Rhw; hb=Rhb; ew=Rew; eb=Reb; }
    else          { sw=Psw; sb=Psb; hw=Phw; hb=Phb; ew=Pew; eb=Peb; }

    int layer, mt, kt = 0, rev = 0;
    if (tt < 6)       { layer = 0; rev = (tt >= 3); mt = tt % 3; }
    else if (tt < 24) { int u = tt - 6; layer = 1 + u / 6; u %= 6; mt = u / 2; kt = u % 2; }
    else              { layer = 4; mt = 0; kt = tt - 24; }

    const int m     = mt * 16 + (l & 15);
    const int kbase = kt * 32 + (l >> 4) * 8;

    unsigned short hi8[8], lo8[8];
    #pragma unroll
    for (int j = 0; j < 8; ++j) {
        const int k = kbase + j;
        float v = 0.0f;
        if (layer == 0) {
            if (m < 35) { if (k < 10) v = sw[m * 10 + (rev ? 9 - k : k)];
                          else if (k == 10) v = sb[m]; }
        } else if (layer <= 3) {
            if (m < 35) { if (k < 35) v = hw[(layer - 1) * 1225 + m * 35 + k];
                          else if (k == 35) v = hb[(layer - 1) * 35 + m]; }
        } else {
            if (m < 5)  { if (k < 35) v = ew[m * 35 + k];
                          else if (k == 35) v = eb[m]; }
        }
        _Float16 h = (_Float16)v;
        _Float16 lo = (_Float16)(v - (float)h);
        hi8[j] = __builtin_bit_cast(unsigned short, h);
        lo8[j] = __builtin_bit_cast(unsigned short, lo);
    }
    unsigned short* bh = frags + ((size_t)(t * 2 + 0) * 64 + l) * 8;
    unsigned short* bl = frags + ((size_t)(t * 2 + 1) * 64 + l) * 8;
    #pragma unroll
    for (int j = 0; j < 8; ++j) { bh[j] = hi8[j]; bl[j] = lo8[j]; }
}

// block-aggregated two-ended compaction by outcome sign
__global__ void __launch_bounds__(256) sort_kernel(
    const float* __restrict__ outcome, int* __restrict__ list, int* __restrict__ cnts)
{
    __shared__ int wTotP[4], wTotN[4], wBaseP[4], wBaseN[4], blkP, blkN;
    const int tid = threadIdx.x, wv = tid >> 6, lane = tid & 63;

    #pragma unroll 1
    for (int start = blockIdx.x * 2048; start < NEDGES; start += gridDim.x * 2048) {
        const int e0 = start + tid * 8;
        int valid[8], isp[8];
        int pc = 0, nc = 0;
        #pragma unroll
        for (int j = 0; j < 8; ++j) {
            const int e = e0 + j;
            valid[j] = (e < NEDGES);
            float o = valid[j] ? outcome[e] : 0.0f;
            isp[j] = valid[j] && (o > 0.0f);
            pc += isp[j];
            nc += (valid[j] && !isp[j]);
        }
        int pi = pc, ni = nc;
        #pragma unroll
        for (int off = 1; off < 64; off <<= 1) {
            int tp = __shfl_up(pi, off);
            int tn = __shfl_up(ni, off);
            if (lane >= off) { pi += tp; ni += tn; }
        }
        const int pex = pi - pc, nex = ni - nc;
        if (lane == 63) { wTotP[wv] = pi; wTotN[wv] = ni; }
        __syncthreads();
        if (tid == 0) {
            int tp = 0, tn = 0;
            #pragma unroll
            for (int w = 0; w < 4; ++w) {
                wBaseP[w] = tp; wBaseN[w] = tn;
                tp += wTotP[w]; tn += wTotN[w];
            }
            blkP = atomicAdd(&cnts[0], tp);
            blkN = atomicAdd(&cnts[1], tn);
        }
        __syncthreads();
        int pbase = blkP + wBaseP[wv] + pex;
        int nbase = blkN + wBaseN[wv] + nex;
        #pragma unroll
        for (int j = 0; j < 8; ++j) {
            if (isp[j])        list[pbase++] = e0 + j;
            else if (valid[j]) list[NEDGES - 1 - (nbase++)] = e0 + j;
        }
        __syncthreads();
    }
}

__device__ __forceinline__ unsigned int pk16(_Float16 a, _Float16 b) {
    return (unsigned int)__builtin_bit_cast(unsigned short, a) |
           ((unsigned int)__builtin_bit_cast(unsigned short, b) << 16);
}

__device__ __forceinline__ void trans_store(unsigned int* hb, int n, int rb, int mt, f32x4 v)
{
    _Float16 h0 = (_Float16)v[0], h1 = (_Float16)v[1], h2 = (_Float16)v[2], h3 = (_Float16)v[3];
    float r0 = v[0] - (float)h0, r1 = v[1] - (float)h1, r2 = v[2] - (float)h2, r3 = v[3] - (float)h3;
    unsigned int hd0 = pk16(h0, h1), hd1 = pk16(h2, h3);
    unsigned int ld0 = pk16((_Float16)r0, (_Float16)r1), ld1 = pk16((_Float16)r2, (_Float16)r3);
    const int b  = 2 * mt + (rb >> 1);
    const int bp = b ^ (n & 7);
    const int dw = n * 32 + (bp << 2) + ((rb & 1) << 1);
    *reinterpret_cast<uint2*>(hb + dw)       = make_uint2(hd0, hd1);
    *reinterpret_cast<uint2*>(hb + 512 + dw) = make_uint2(ld0, ld1);
}

__device__ __forceinline__ f16x8 read_b(const unsigned int* hb, int n, int kb, int kt, int lobuf)
{
    const int b  = kt * 4 + kb;
    const int bp = b ^ (n & 7);
    uint4 d = *reinterpret_cast<const uint4*>(hb + lobuf * 512 + n * 32 + (bp << 2));
    return __builtin_bit_cast(f16x8, d);
}

#define MF(acc, WH, WL, BH, BL)                                                    \
    acc = __builtin_amdgcn_mfma_f32_16x16x32_f16(WH, BH, acc, 0, 0, 0);            \
    acc = __builtin_amdgcn_mfma_f32_16x16x32_f16(WH, BL, acc, 0, 0, 0);            \
    acc = __builtin_amdgcn_mfma_f32_16x16x32_f16(WL, BH, acc, 0, 0, 0);

#define TRANSITION(X0, X1, X2)                                                     \
    {                                                                              \
        _Pragma("unroll")                                                          \
        for (int r = 0; r < 4; ++r) {                                              \
            X0[r] = fmaxf(X0[r], 0.0f);                                            \
            X1[r] = fmaxf(X1[r], 0.0f);                                            \
            X2[r] = fmaxf(X2[r], 0.0f);                                            \
        }                                                                          \
        if (kb == 0) X2[3] = 1.0f;                                                 \
        trans_store(hb, n, kb, 0, X0);                                             \
        trans_store(hb, n, kb, 1, X1);                                             \
        trans_store(hb, n, kb, 2, X2);                                             \
    }

#define HLAYER(U0, C0, C1, C2)                                                     \
    {                                                                              \
        f16x8 bh0 = read_b(hb, n, kb, 0, 0), bl0 = read_b(hb, n, kb, 0, 1);        \
        f16x8 bh1 = read_b(hb, n, kb, 1, 0), bl1 = read_b(hb, n, kb, 1, 1);        \
        C0 = z4; C1 = z4; C2 = z4;                                                 \
        __builtin_amdgcn_s_setprio(1);                                             \
        MF(C0, wh[(U0) + 0], wl[(U0) + 0], bh0, bl0)                               \
        MF(C0, wh[(U0) + 1], wl[(U0) + 1], bh1, bl1)                               \
        MF(C1, wh[(U0) + 2], wl[(U0) + 2], bh0, bl0)                               \
        MF(C1, wh[(U0) + 3], wl[(U0) + 3], bh1, bl1)                               \
        MF(C2, wh[(U0) + 4], wl[(U0) + 4], bh0, bl0)                               \
        MF(C2, wh[(U0) + 5], wl[(U0) + 5], bh1, bl1)                               \
        __builtin_amdgcn_s_setprio(0);                                             \
    }

// MODE 0: f64-packed atomics (fallback). MODE 1: stream u64 records (atomic-free).
template<int MODE>
__global__ void __launch_bounds__(256, 2) edge_kernel(
    const float* __restrict__ score,
    const int*   __restrict__ edge_idx,
    const unsigned short* __restrict__ frags,
    const int*   __restrict__ list,
    const int*   __restrict__ cnts,
    double* __restrict__ aggd,
    unsigned long long* __restrict__ recs)
{
    __shared__ unsigned int hbuf[4][1024];
    const int tid  = threadIdx.x;
    const int wv   = tid >> 6;
    const int lane = tid & 63;
    const int n    = lane & 15;
    const int kb   = lane >> 4;
    const int k0   = kb * 8;
    unsigned int* hb = &hbuf[wv][0];

    for (int i = lane; i < 1024; i += 64) hb[i] = 0;

    const int gw    = blockIdx.x * 4 + wv;
    const int combo = gw & 3;
    const int wci   = gw >> 2;

    const int cp   = cnts[0];
    const int useR = (combo < 2);
    const int rev  = (combo == 1 || combo == 2);
    const float sgn = useR ? 1.0f : -1.0f;
    const int lo_  = (combo == 0 || combo == 2) ? 0 : cp;
    const int hi_  = (combo == 0 || combo == 2) ? cp : NEDGES;
    const int cnt  = hi_ - lo_;
    const int revoff = rev ? 5 : 0;
    const int t0   = useR ? 0 : NTILES_PER_NET;

    f16x8 wh[18], wl[18];
    #pragma unroll
    for (int u = 0; u < 18; ++u) {
        const int t = t0 + 6 + u;
        wh[u] = *reinterpret_cast<const f16x8*>(frags + ((size_t)(t * 2 + 0) * 64 + lane) * 8);
        wl[u] = *reinterpret_cast<const f16x8*>(frags + ((size_t)(t * 2 + 1) * 64 + lane) * 8);
    }
    f16x8 w0h[3], w0l[3], w4h[2], w4l[2];
    #pragma unroll
    for (int mt = 0; mt < 3; ++mt) {
        const int t = t0 + (rev ? 3 : 0) + mt;
        w0h[mt] = *reinterpret_cast<const f16x8*>(frags + ((size_t)(t * 2 + 0) * 64 + lane) * 8);
        w0l[mt] = *reinterpret_cast<const f16x8*>(frags + ((size_t)(t * 2 + 1) * 64 + lane) * 8);
    }
    #pragma unroll
    for (int kt = 0; kt < 2; ++kt) {
        const int t = t0 + 24 + kt;
        w4h[kt] = *reinterpret_cast<const f16x8*>(frags + ((size_t)(t * 2 + 0) * 64 + lane) * 8);
        w4l[kt] = *reinterpret_cast<const f16x8*>(frags + ((size_t)(t * 2 + 1) * 64 + lane) * 8);
    }

    const f32x4 z4 = {0.0f, 0.0f, 0.0f, 0.0f};

    auto GATHER = [&](int b, float (&s)[8], int& edo, bool& ao) {
        ao  = (b + n) < cnt;
        edo = list[ao ? (lo_ + b + n) : lo_];
        #pragma unroll
        for (int j = 0; j < 8; ++j) {
            const int k = k0 + j;
            const int id = (k < 10) ? edge_idx[edo * 10 + k] : 0;
            s[j] = (k < 10) ? score[id] : 0.0f;
        }
        if (kb == 1) s[2] = 1.0f;
    };

    int   base = wci * 16;
    float sc[8];
    int   ecur = 0;
    bool  act  = false;
    if (base < cnt) GATHER(base, sc, ecur, act);

    #pragma unroll 1
    for (; base < cnt; ) {
        const int nbase = base + (int)gridDim.x * 16;
        float scn[8];
        int   enx  = 0;
        bool  actn = false;
        if (nbase < cnt) GATHER(nbase, scn, enx, actn);

        f16x8 bxh, bxl;
        #pragma unroll
        for (int j = 0; j < 8; ++j) {
            _Float16 h = (_Float16)sc[j];
            bxh[j] = h;
            bxl[j] = (_Float16)(sc[j] - (float)h);
        }

        f32x4 a0 = z4, a1 = z4, a2 = z4;
        __builtin_amdgcn_s_setprio(1);
        MF(a0, w0h[0], w0l[0], bxh, bxl)
        MF(a1, w0h[1], w0l[1], bxh, bxl)
        MF(a2, w0h[2], w0l[2], bxh, bxl)
        __builtin_amdgcn_s_setprio(0);
        TRANSITION(a0, a1, a2)

        f32x4 c0, c1, c2;
        HLAYER(0, c0, c1, c2)
        TRANSITION(c0, c1, c2)
        HLAYER(6, c0, c1, c2)
        TRANSITION(c0, c1, c2)
        HLAYER(12, c0, c1, c2)
        TRANSITION(c0, c1, c2)

        f32x4 c4 = z4;
        {
            f16x8 bh0 = read_b(hb, n, kb, 0, 0), bl0 = read_b(hb, n, kb, 0, 1);
            f16x8 bh1 = read_b(hb, n, kb, 1, 0), bl1 = read_b(hb, n, kb, 1, 1);
            __builtin_amdgcn_s_setprio(1);
            MF(c4, w4h[0], w4l[0], bh0, bl0)
            MF(c4, w4h[1], w4l[1], bh1, bl1)
            __builtin_amdgcn_s_setprio(0);
        }

        #pragma unroll
        for (int r = 0; r < 4; ++r) {
            const int q = kb * 4 + r;
            if (act && q < 5) {
                const float v = sgn / (1.0f + __expf(-c4[r]));
                const int tgt = edge_idx[ecur * 10 + revoff + q];
                if (MODE == 0) {
                    unsafeAtomicAdd(&aggd[tgt], (double)v + PK_SCALE);
                } else {
                    const unsigned long long rcd =
                        ((unsigned long long)(unsigned)tgt << 32) |
                        (unsigned long long)__float_as_uint(v);
                    recs[(long long)(lo_ + base + n) * 10 + revoff + q] = rcd;
                }
            }
        }

        base = nbase;
        #pragma unroll
        for (int j = 0; j < 8; ++j) sc[j] = scn[j];
        ecur = enx;
        act  = actn;
    }
}

// ---- counting-sort pipeline (atomic-free aggregation) ----

__global__ void __launch_bounds__(256) hist_kernel(const unsigned long long* __restrict__ recs,
                                                   unsigned* __restrict__ hist)
{
    __shared__ unsigned h[256];
    const int t = threadIdx.x;
    h[t] = 0;
    __syncthreads();
    const long long lo = (long long)blockIdx.x * S3_CHUNK;
    const long long hi = (lo + S3_CHUNK < NREC) ? lo + S3_CHUNK : NREC;
    for (long long i = lo + t; i < hi; i += 256)
        atomicAdd(&h[(unsigned)(recs[i] >> 41)], 1u);
    __syncthreads();
    hist[blockIdx.x * 256 + t] = h[t];
}

__global__ void __launch_bounds__(256) colscan_kernel(const unsigned* __restrict__ hist,
                                                      unsigned* __restrict__ offs,
                                                      unsigned* __restrict__ colT)
{
    const int b = blockIdx.x;       // bucket column 0..255
    const int t = threadIdx.x, lane = t & 63, wv = t >> 6;
    unsigned v[8]; unsigned s = 0;
    #pragma unroll
    for (int j = 0; j < 8; ++j) { v[j] = hist[(t * 8 + j) * 256 + b]; s += v[j]; }
    unsigned si = s;
    #pragma unroll
    for (int off = 1; off < 64; off <<= 1) {
        unsigned tv = __shfl_up(si, off);
        if (lane >= off) si += tv;
    }
    __shared__ unsigned wt[4], wb[4];
    if (lane == 63) wt[wv] = si;
    __syncthreads();
    if (t == 0) {
        unsigned a = 0;
        #pragma unroll
        for (int w = 0; w < 4; ++w) { wb[w] = a; a += wt[w]; }
        colT[b] = a;
    }
    __syncthreads();
    unsigned basee = wb[wv] + (si - s);
    #pragma unroll
    for (int j = 0; j < 8; ++j) { offs[(t * 8 + j) * 256 + b] = basee; basee += v[j]; }
}

__global__ void basescan_kernel(const unsigned* __restrict__ colT, unsigned* __restrict__ base)
{
    if (threadIdx.x == 0) {
        unsigned a = 0;
        for (int b = 0; b < 256; ++b) { base[b] = a; a += colT[b]; }
        base[256] = a;
    }
}

__global__ void __launch_bounds__(256) scatter_kernel(const unsigned long long* __restrict__ recs,
                                                      const unsigned* __restrict__ offs,
                                                      const unsigned* __restrict__ base,
                                                      unsigned long long* __restrict__ binned)
{
    __shared__ unsigned cur[256];
    const int t = threadIdx.x;
    cur[t] = offs[blockIdx.x * 256 + t] + base[t];
    __syncthreads();
    const long long lo = (long long)blockIdx.x * S3_CHUNK;
    const long long hi = (lo + S3_CHUNK < NREC) ? lo + S3_CHUNK : NREC;
    for (long long i = lo + t; i < hi; i += 256) {
        const unsigned long long r = recs[i];
        const unsigned p = atomicAdd(&cur[(unsigned)(r >> 41)], 1u);
        binned[p] = r;
    }
}

__global__ void __launch_bounds__(256) reduce_kernel(const unsigned long long* __restrict__ binned,
                                                     const unsigned* __restrict__ base,
                                                     float* __restrict__ agg,
                                                     int* __restrict__ deg)
{
    __shared__ unsigned long long bins[512];
    const int t = threadIdx.x;
    bins[t] = 0; bins[t + 256] = 0;
    __syncthreads();
    const int b = blockIdx.x;
    const unsigned lo = base[b], hi = base[b + 1];
    for (unsigned i = lo + t; i < hi; i += 256) {
        const unsigned long long r = binned[i];
        const int local = (int)((r >> 32) & 511);
        const float v = __uint_as_float((unsigned)r);
        const long long c = (long long)llrintf(v * 4294967296.0f) + (1ll << 44);
        atomicAdd(&bins[local], (unsigned long long)c);
    }
    __syncthreads();
    #pragma unroll
    for (int j = 0; j < 2; ++j) {
        const int local = t + j * 256;
        const int node = b * 512 + local;
        if (node < NNODES) {
            const unsigned long long T = bins[local];
            const long long d = (long long)((T + (1ll << 43)) >> 44);
            const long long S = (long long)(T - ((unsigned long long)d << 44));
            agg[node] = (float)((double)S * (1.0 / 4294967296.0));
            deg[node] = (int)d;
        }
    }
}

// ---- tails (fast path: f32 agg + int deg) ----
__global__ void __launch_bounds__(256) degmax_kernel(const int* __restrict__ deg,
                                                     int* __restrict__ degmax)
{
    int m = 0;
    for (int i = blockIdx.x * blockDim.x + threadIdx.x; i < NNODES; i += gridDim.x * blockDim.x)
        m = max(m, deg[i]);
    #pragma unroll
    for (int off = 32; off; off >>= 1) m = max(m, __shfl_down(m, off));
    __shared__ int sm[4];
    if ((threadIdx.x & 63) == 0) sm[threadIdx.x >> 6] = m;
    __syncthreads();
    if (threadIdx.x == 0) {
        int mm = sm[0];
        #pragma unroll
        for (int w = 1; w < 4; ++w) mm = max(mm, sm[w]);
        atomicMax(degmax, mm);
    }
}

__global__ void __launch_bounds__(256) stats_kernel(const float* __restrict__ score,
                                                    const float* __restrict__ agg,
                                                    const int* __restrict__ degmax,
                                                    float* __restrict__ stats)
{
    const float scale = 2.0f / (float)(*degmax);
    float s = 0.0f, s2 = 0.0f;
    for (int i = blockIdx.x * blockDim.x + threadIdx.x; i < NNODES; i += gridDim.x * blockDim.x) {
        float v = fmaf(agg[i], scale, score[i]);
        s += v;
        s2 = fmaf(v, v, s2);
    }
    #pragma unroll
    for (int off = 32; off; off >>= 1) { s += __shfl_down(s, off); s2 += __shfl_down(s2, off); }
    __shared__ float ssum[4], ssq[4];
    if ((threadIdx.x & 63) == 0) { ssum[threadIdx.x >> 6] = s; ssq[threadIdx.x >> 6] = s2; }
    __syncthreads();
    if (threadIdx.x == 0) {
        float a = 0.0f, b = 0.0f;
        #pragma unroll
        for (int w = 0; w < 4; ++w) { a += ssum[w]; b += ssq[w]; }
        unsafeAtomicAdd(&stats[0], a);
        unsafeAtomicAdd(&stats[1], b);
    }
}

__global__ void __launch_bounds__(256) finalize_kernel(const float* __restrict__ score,
                                                       const float* __restrict__ agg,
                                                       const int* __restrict__ degmax,
                                                       const float* __restrict__ stats,
                                                       float* __restrict__ out)
{
    const float scale = 2.0f / (float)(*degmax);
    const float sum = stats[0], sumsq = stats[1];
    const float mean = sum * (1.0f / NNODES);
    const float rn = 1.0f / sqrtf(sumsq - sum * mean);
    for (int i = blockIdx.x * blockDim.x + threadIdx.x; i < NNODES; i += gridDim.x * blockDim.x) {
        float v = fmaf(agg[i], scale, score[i]);
        out[i] = (v - mean) * rn;
    }
}

// ---- tails (fallback path: f64-packed aggd) ----
__global__ void __launch_bounds__(256) degmax_pk(const double* __restrict__ aggd,
                                                 int* __restrict__ degmax)
{
    int m = 0;
    for (int i = blockIdx.x * blockDim.x + threadIdx.x; i < NNODES; i += gridDim.x * blockDim.x)
        m = max(m, (int)(aggd[i] * PK_INV + 0.5));
    #pragma unroll
    for (int off = 32; off; off >>= 1) m = max(m, __shfl_down(m, off));
    __shared__ int sm[4];
    if ((threadIdx.x & 63) == 0) sm[threadIdx.x >> 6] = m;
    __syncthreads();
    if (threadIdx.x == 0) {
        int mm = sm[0];
        #pragma unroll
        for (int w = 1; w < 4; ++w) mm = max(mm, sm[w]);
        atomicMax(degmax, mm);
    }
}

__global__ void __launch_bounds__(256) stats_pk(const float* __restrict__ score,
                                                const double* __restrict__ aggd,
                                                const int* __restrict__ degmax,
                                                float* __restrict__ stats)
{
    const float scale = 2.0f / (float)(*degmax);
    float s = 0.0f, s2 = 0.0f;
    for (int i = blockIdx.x * blockDim.x + threadIdx.x; i < NNODES; i += gridDim.x * blockDim.x) {
        const double T = aggd[i];
        const int d = (int)(T * PK_INV + 0.5);
        const float vs = (float)(T - (double)d * PK_SCALE);
        float v = fmaf(vs, scale, score[i]);
        s += v;
        s2 = fmaf(v, v, s2);
    }
    #pragma unroll
    for (int off = 32; off; off >>= 1) { s += __shfl_down(s, off); s2 += __shfl_down(s2, off); }
    __shared__ float ssum[4], ssq[4];
    if ((threadIdx.x & 63) == 0) { ssum[threadIdx.x >> 6] = s; ssq[threadIdx.x >> 6] = s2; }
    __syncthreads();
    if (threadIdx.x == 0) {
        float a = 0.0f, b = 0.0f;
        #pragma unroll
        for (int w = 0; w < 4; ++w) { a += ssum[w]; b += ssq[w]; }
        unsafeAtomicAdd(&stats[0], a);
        unsafeAtomicAdd(&stats[1], b);
    }
}

__global__ void __launch_bounds__(256) finalize_pk(const float* __restrict__ score,
                                                   const double* __restrict__ aggd,
                                                   const int* __restrict__ degmax,
                                                   const float* __restrict__ stats,
                                                   float* __restrict__ out)
{
    const float scale = 2.0f / (float)(*degmax);
    const float sum = stats[0], sumsq = stats[1];
    const float mean = sum * (1.0f / NNODES);
    const float rn = 1.0f / sqrtf(sumsq - sum * mean);
    for (int i = blockIdx.x * blockDim.x + threadIdx.x; i < NNODES; i += gridDim.x * blockDim.x) {
        const double T = aggd[i];
        const int d = (int)(T * PK_INV + 0.5);
        const float vs = (float)(T - (double)d * PK_SCALE);
        float v = fmaf(vs, scale, score[i]);
        out[i] = (v - mean) * rn;
    }
}

extern "C" void kernel_launch(void* const* d_in, const int* in_sizes, int n_in,
                              void* d_out, int out_size, void* d_ws, size_t ws_size,
                              hipStream_t stream)
{
    const float* score    = (const float*)d_in[0];
    const int*   edge_idx = (const int*)  d_in[1];
    const float* outcome  = (const float*)d_in[2];
    const float* Rsw = (const float*)d_in[3];
    const float* Rsb = (const float*)d_in[4];
    const float* Rhw = (const float*)d_in[5];
    const float* Rhb = (const float*)d_in[6];
    const float* Rew = (const float*)d_in[7];
    const float* Reb = (const float*)d_in[8];
    const float* Psw = (const float*)d_in[9];
    const float* Psb = (const float*)d_in[10];
    const float* Phw = (const float*)d_in[11];
    const float* Phb = (const float*)d_in[12];
    const float* Pew = (const float*)d_in[13];
    const float* Peb = (const float*)d_in[14];
    float* out = (float*)d_out;

    char* ws = (char*)d_ws;
    float*              agg    = (float*)(ws + WS_AGG);
    int*                deg    = (int*)  (ws + WS_DEG);
    double*             aggd   = (double*)(ws + WS_AGG);
    float*              stats  = (float*)(ws + WS_STATS);
    int*                degmax = (int*)  (ws + WS_DEGMAX);
    int*                cnts   = (int*)  (ws + WS_CNTS);
    unsigned short*     frags  = (unsigned short*)(ws + WS_FRAGS);
    int*                list   = (int*)  (ws + WS_LIST);
    unsigned*           basep  = (unsigned*)(ws + WS_BASE);
    unsigned*           colT   = (unsigned*)(ws + WS_COLT);
    unsigned*           hist   = (unsigned*)(ws + WS_HIST);
    unsigned*           offs   = (unsigned*)(ws + WS_OFFS);
    unsigned long long* recs   = (unsigned long long*)(ws + WS_RECS);
    unsigned long long* binned = (unsigned long long*)(ws + WS_BINN);

    const bool fast = (ws_size >= (size_t)WS_NEED);
    const int nb = (NNODES + 255) / 256;

    prep_frag_kernel<<<52, 64, 0, stream>>>(Rsw, Rsb, Rhw, Rhb, Rew, Reb,
                                            Psw, Psb, Phw, Phb, Pew, Peb, frags);

    if (fast) {
        hipMemsetAsync(ws + WS_STATS, 0, WS_ZERO_END - WS_STATS, stream);
        sort_kernel<<<256, 256, 0, stream>>>(outcome, list, cnts);
        edge_kernel<1><<<2048, 256, 0, stream>>>(score, edge_idx, frags, list, cnts, aggd, recs);
        hist_kernel    <<<S3_BLOCKS, 256, 0, stream>>>(recs, hist);
        colscan_kernel <<<256, 256, 0, stream>>>(hist, offs, colT);
        basescan_kernel<<<1, 64, 0, stream>>>(colT, basep);
        scatter_kernel <<<S3_BLOCKS, 256, 0, stream>>>(recs, offs, basep, binned);
        reduce_kernel  <<<196, 256, 0, stream>>>(binned, basep, agg, deg);
        degmax_kernel  <<<nb, 256, 0, stream>>>(deg, degmax);
        stats_kernel   <<<nb, 256, 0, stream>>>(score, agg, degmax, stats);
        finalize_kernel<<<nb, 256, 0, stream>>>(score, agg, degmax, stats, out);
    } else {
        hipMemsetAsync(d_ws, 0, WS_ZERO_END, stream);
        sort_kernel<<<256, 256, 0, stream>>>(outcome, list, cnts);
        edge_kernel<0><<<2048, 256, 0, stream>>>(score, edge_idx, frags, list, cnts, aggd, recs);
        degmax_pk  <<<nb, 256, 0, stream>>>(aggd, degmax);
        stats_pk   <<<nb, 256, 0, stream>>>(score, aggd, degmax, stats);
        finalize_pk<<<nb, 256, 0, stream>>>(score, aggd, degmax, stats, out);
    }
}